// Round 9
// baseline (401.638 us; speedup 1.0000x reference)
//
#include <hip/hip_runtime.h>
#include <math.h>

#define BB 1024
#define LL 40
#define RR 1024

using short8 = __attribute__((ext_vector_type(8))) short;
using us8    = __attribute__((ext_vector_type(8))) unsigned short;
using f32x4  = __attribute__((ext_vector_type(4))) float;

__device__ __forceinline__ ushort f2bf(float f) {
    union { float f; unsigned u; } a; a.f = f;
    unsigned r = a.u + 0x7fffu + ((a.u >> 16) & 1u);  // RNE
    return (ushort)(r >> 16);
}
__device__ __forceinline__ float bf2f(ushort u) {
    union { unsigned u; float f; } a; a.u = ((unsigned)u) << 16;
    return a.f;
}
__device__ __forceinline__ float ftanh(float x) {
    float cx = fminf(fmaxf(x, -15.f), 15.f);
    float e = __expf(2.f * cx);
    return (e - 1.f) / (e + 1.f);
}
__device__ __forceinline__ float fsigmoid(float x) {
    float cx = fminf(fmaxf(x, -30.f), 30.f);
    return 1.f / (1.f + __expf(-cx));
}

__device__ __forceinline__ void gll16(const ushort* g, ushort* l) {
    __builtin_amdgcn_global_load_lds(
        (const __attribute__((address_space(1))) void*)g,
        (__attribute__((address_space(3))) void*)l,
        16, 0, 0);
}

// ---------------------------------------------------------------------------
__global__ __launch_bounds__(256) void conv_bf16_kernel(
    const float* __restrict__ src, ushort* __restrict__ dst, int n8)
{
    const int i = blockIdx.x * 256 + threadIdx.x;
    if (i >= n8) return;
    const float4* s4 = (const float4*)(src + (size_t)i * 8);
    float4 x = s4[0], y = s4[1];
    us8 v;
    v[0] = f2bf(x.x); v[1] = f2bf(x.y); v[2] = f2bf(x.z); v[3] = f2bf(x.w);
    v[4] = f2bf(y.x); v[5] = f2bf(y.y); v[6] = f2bf(y.z); v[7] = f2bf(y.w);
    ((us8*)dst)[i] = v;
}

struct CP3 { const float* in[3]; ushort* out[3]; };
__global__ __launch_bounds__(256) void conv_bf16_batch3_kernel(CP3 p, int n8)
{
    const int z = blockIdx.y;
    const int i = blockIdx.x * 256 + threadIdx.x;
    if (i >= n8) return;
    const float4* s4 = (const float4*)(p.in[z] + (size_t)i * 8);
    float4 x = s4[0], y = s4[1];
    us8 v;
    v[0] = f2bf(x.x); v[1] = f2bf(x.y); v[2] = f2bf(x.z); v[3] = f2bf(x.w);
    v[4] = f2bf(y.x); v[5] = f2bf(y.y); v[6] = f2bf(y.z); v[7] = f2bf(y.w);
    ((us8*)p.out[z])[i] = v;
}

struct TP6 { const float* in[6]; ushort* out[6]; int N[6]; };
__global__ __launch_bounds__(256) void transpose_conv_kernel(TP6 p)
{
    const int z = blockIdx.z;
    const int Nn = p.N[z];
    const int n0 = blockIdx.x * 64;
    if (n0 >= Nn) return;
    const int k0 = blockIdx.y * 64;
    const float* in = p.in[z];
    ushort* out = p.out[z];

    __shared__ float tile[64][65];
    const int t = threadIdx.x;
    const int tx = t & 63, ty = t >> 6;
#pragma unroll
    for (int r = 0; r < 16; ++r) {
        const int row = ty * 16 + r;
        tile[row][tx] = in[(size_t)(k0 + row) * Nn + n0 + tx];
    }
    __syncthreads();
    const int n = t >> 2, kq = t & 3;
    us8 v0, v1;
#pragma unroll
    for (int j = 0; j < 8; ++j) v0[j] = f2bf(tile[kq * 16 + j][n]);
#pragma unroll
    for (int j = 0; j < 8; ++j) v1[j] = f2bf(tile[kq * 16 + 8 + j][n]);
    ushort* op = out + (size_t)(n0 + n) * 1024 + k0 + kq * 16;
    *(us8*)op = v0;
    *((us8*)op + 1) = v1;
}

// ---------------------------------------------------------------------------
// 8-phase 256x256 BK=64 GEMM (T3+T4). 512 threads = 8 waves (2M x 4N).
// Per-wave output 128x64 interleaved: rows {wm*64, 128+wm*64}, cols
// {wn*32, 128+wn*32}. Per tile: 4 phases, each stages ONE half-tile of
// tile T+1 (2 gll16/thread), waits vmcnt(4), barrier, ds_reads one
// quadrant (Ah=q&1, Bh=q>>1), 16 MFMA. Stage order [A-H0,B-H0,A-H1,B-H1]
// guarantees vmcnt(4) covers each quadrant's data (ledger in comments).
// XOR-swizzled LDS (R8-verified, 0 bank conflicts).
// EPI: 2 = attn tanh-reduce -> epart[row*2+nblk]; 3 = bf16 split-K partial.
// ---------------------------------------------------------------------------
template <int NP, int NTZ, int EPI>
__global__ __launch_bounds__(512) void gemm8p(
    const ushort* __restrict__ A0, const ushort* __restrict__ A1, const ushort* __restrict__ A2,
    const ushort* __restrict__ W0, const ushort* __restrict__ W1, const ushort* __restrict__ W2,
    ushort* __restrict__ Cp, int M, int N,
    const float* __restrict__ hq, const float* __restrict__ bv2a,
    const float* __restrict__ Wa2w, float* __restrict__ epart)
{
    __shared__ ushort As[2][256 * 64];   // 64 KB (2 buf x 32 KB)
    __shared__ ushort Bs[2][256 * 64];   // 64 KB

    const int t = threadIdx.x, l = t & 63, w = t >> 6;
    const int wm = w >> 2, wn = w & 3;   // 2 x 4 wave grid

    int mblk, nblk, bz;
    if constexpr (EPI == 2) {
        const int lin = blockIdx.x;                 // 320 = 8*40, bijective
        const int swz = (lin & 7) * 40 + (lin >> 3);
        nblk = swz & 1; mblk = swz >> 1; bz = 0;
    } else {
        mblk = blockIdx.x; nblk = blockIdx.y; bz = blockIdx.z;
    }
    const int m0 = mblk * 256, n0 = nblk * 256;

    f32x4 acc[2][4][2][2];
#pragma unroll
    for (int a = 0; a < 2; ++a)
#pragma unroll
        for (int b = 0; b < 4; ++b)
#pragma unroll
            for (int c = 0; c < 2; ++c)
#pragma unroll
                for (int d = 0; d < 2; ++d) acc[a][b][c][d] = (f32x4){0.f, 0.f, 0.f, 0.f};

    const int csw = ((l & 7) ^ (l >> 3)) * 8;   // pre-swizzled source chunk
    const int kx0 = ((0 + (l >> 4)) ^ (l & 7)) * 8;
    const int kx1 = ((4 + (l >> 4)) ^ (l & 7)) * 8;

    const int s0 = bz * NTZ;

    // stage half-tile q' of tile s: q'={0:A-H0, 1:B-H0, 2:A-H1, 3:B-H1}
    auto stage = [&](int s, int q) {
        const int p  = (NP == 1) ? 0 : (s >> 4);
        const int k0 = (s & 15) << 6;
        const ushort* src;
        ushort* dst;
        int x0;
        if (q & 1) {
            src = (p == 0) ? W0 : ((p == 1) ? W1 : W2);
            dst = &Bs[s & 1][0]; x0 = n0;
        } else {
            src = (p == 0) ? A0 : ((p == 1) ? A1 : A2);
            dst = &As[s & 1][0]; x0 = m0;
        }
        const int h = q >> 1;
#pragma unroll
        for (int j = 0; j < 2; ++j) {
            const int rb = h * 128 + j * 64 + w * 8;
            gll16(src + (size_t)(x0 + rb + (l >> 3)) * 1024 + k0 + csw, dst + rb * 64);
        }
    };

    // prologue: stage tile s0's 4 halves (8 loads outstanding)
    stage(s0, 0); stage(s0, 1); stage(s0, 2); stage(s0, 3);

    for (int ti = 0; ti < NTZ; ++ti) {
        const int s = s0 + ti;
        const ushort* Ab = &As[s & 1][0];
        const ushort* Bb = &Bs[s & 1][0];
        const bool last = (ti == NTZ - 1);
        if (last) {   // no more stages -> drain once, then run phases dry
            asm volatile("s_waitcnt vmcnt(0)" ::: "memory");
            __builtin_amdgcn_s_barrier();
            asm volatile("" ::: "memory");
        }
#pragma unroll
        for (int q = 0; q < 4; ++q) {
            if (!last) {
                stage(s + 1, q);
                // ledger: after this stage, <=6 loads outstanding; vmcnt(4)
                // retires all stages >=2 phases old, exactly covering the
                // half-tiles quadrant q reads (stage order vs compute order).
                asm volatile("s_waitcnt vmcnt(4)" ::: "memory");
            }
            __builtin_amdgcn_s_barrier();
            asm volatile("" ::: "memory");

            const int Ah = q & 1, Bh = q >> 1;
            short8 aF[4][2], bF[2][2];
#pragma unroll
            for (int fm = 0; fm < 4; ++fm) {
                const int ro = (Ah * 128 + wm * 64 + fm * 16 + (l & 15)) * 64;
                aF[fm][0] = *(const short8*)&Ab[ro + kx0];
                aF[fm][1] = *(const short8*)&Ab[ro + kx1];
            }
#pragma unroll
            for (int fn = 0; fn < 2; ++fn) {
                const int co = (Bh * 128 + wn * 32 + fn * 16 + (l & 15)) * 64;
                bF[fn][0] = *(const short8*)&Bb[co + kx0];
                bF[fn][1] = *(const short8*)&Bb[co + kx1];
            }
            __builtin_amdgcn_s_setprio(1);
#pragma unroll
            for (int fm = 0; fm < 4; ++fm)
#pragma unroll
                for (int fn = 0; fn < 2; ++fn) {
                    acc[Ah][fm][Bh][fn] = __builtin_amdgcn_mfma_f32_16x16x32_bf16(
                        aF[fm][0], bF[fn][0], acc[Ah][fm][Bh][fn], 0, 0, 0);
                    acc[Ah][fm][Bh][fn] = __builtin_amdgcn_mfma_f32_16x16x32_bf16(
                        aF[fm][1], bF[fn][1], acc[Ah][fm][Bh][fn], 0, 0, 0);
                }
            __builtin_amdgcn_s_setprio(0);
        }
        // tile boundary: all reads of this buffer done before it is restaged
        asm volatile("" ::: "memory");
        __builtin_amdgcn_s_barrier();
        asm volatile("" ::: "memory");
    }

    if constexpr (EPI == 3) {
        ushort* Cz = Cp + (size_t)bz * M * N;
#pragma unroll
        for (int fmh = 0; fmh < 2; ++fmh)
#pragma unroll
            for (int fm = 0; fm < 4; ++fm) {
                const int row = m0 + fmh * 128 + wm * 64 + fm * 16 + ((l >> 4) << 2);
#pragma unroll
                for (int fnh = 0; fnh < 2; ++fnh)
#pragma unroll
                    for (int fn = 0; fn < 2; ++fn) {
                        const int col = n0 + fnh * 128 + wn * 32 + fn * 16 + (l & 15);
#pragma unroll
                        for (int r = 0; r < 4; ++r)
                            Cz[(size_t)(row + r) * N + col] = f2bf(acc[fmh][fm][fnh][fn][r]);
                    }
            }
    } else if constexpr (EPI == 2) {
        float* red = (float*)&As[0][0];   // [256][4]
        float wa[2][2], bv[2][2];
        int coln[2][2];
#pragma unroll
        for (int fnh = 0; fnh < 2; ++fnh)
#pragma unroll
            for (int fn = 0; fn < 2; ++fn) {
                coln[fnh][fn] = n0 + fnh * 128 + wn * 32 + fn * 16 + (l & 15);
                wa[fnh][fn] = Wa2w[coln[fnh][fn]];
                bv[fnh][fn] = bv2a[coln[fnh][fn]];
            }
#pragma unroll
        for (int fmh = 0; fmh < 2; ++fmh)
#pragma unroll
            for (int fm = 0; fm < 4; ++fm) {
                const int rl = fmh * 128 + wm * 64 + fm * 16 + ((l >> 4) << 2);
#pragma unroll
                for (int r = 0; r < 4; ++r) {
                    const int row = m0 + rl + r;
                    const int b = row / LL;
                    float v = 0.f;
#pragma unroll
                    for (int fnh = 0; fnh < 2; ++fnh)
#pragma unroll
                        for (int fn = 0; fn < 2; ++fn) {
                            float x = acc[fmh][fm][fnh][fn][r]
                                      + hq[(size_t)b * 512 + coln[fnh][fn]] + bv[fnh][fn];
                            v += ftanh(x) * wa[fnh][fn];
                        }
                    v += __shfl_xor(v, 1);
                    v += __shfl_xor(v, 2);
                    v += __shfl_xor(v, 4);
                    v += __shfl_xor(v, 8);
                    if ((l & 15) == 0) red[(rl + r) * 4 + wn] = v;
                }
            }
        __syncthreads();
        if (t < 256) {
            float s = red[t * 4] + red[t * 4 + 1] + red[t * 4 + 2] + red[t * 4 + 3];
            epart[(size_t)(m0 + t) * 2 + nblk] = s;
        }
    }
}

// ---------------------------------------------------------------------------
// R8 128x128 BK=64 gemm (proven) for the small hq/gate GEMMs. EPI=3 only.
// ---------------------------------------------------------------------------
template <int NP, int SK>
__global__ __launch_bounds__(256) void gemm_gl(
    const ushort* __restrict__ A0, const ushort* __restrict__ A1, const ushort* __restrict__ A2,
    const ushort* __restrict__ W0, const ushort* __restrict__ W1, const ushort* __restrict__ W2,
    ushort* __restrict__ Cp, int M, int N)
{
    __shared__ ushort As[128 * 64];
    __shared__ ushort Bs[128 * 64];

    const int t = threadIdx.x, l = t & 63, w = t >> 6;
    const int wm = w >> 1, wn = w & 1;
    const int m0 = blockIdx.y * 128, n0 = blockIdx.x * 128;

    const int srow = l >> 3;
    const int csw  = ((l & 7) ^ (l >> 3)) * 8;
    const int kx0 = ((0 + (l >> 4)) ^ (l & 7)) * 8;
    const int kx1 = ((4 + (l >> 4)) ^ (l & 7)) * 8;

    f32x4 acc[4][4];
#pragma unroll
    for (int i = 0; i < 4; ++i)
#pragma unroll
        for (int j = 0; j < 4; ++j) acc[i][j] = (f32x4){0.f, 0.f, 0.f, 0.f};

    const int total = NP * 16;
    const int per   = total / SK;
    const int s0v   = blockIdx.z * per;
    const int sEnd  = s0v + per;

    for (int s = s0v; s < sEnd; ++s) {
        const int p  = (NP == 1) ? 0 : (s >> 4);
        const int k0 = (s & 15) << 6;
        const ushort* Ap = (p == 0) ? A0 : ((p == 1) ? A1 : A2);
        const ushort* Wp = (p == 0) ? W0 : ((p == 1) ? W1 : W2);
#pragma unroll
        for (int j = 0; j < 4; ++j) {
            const int rb = w * 32 + j * 8;
            gll16(Ap + (size_t)(m0 + rb + srow) * 1024 + k0 + csw, &As[rb * 64]);
            gll16(Wp + (size_t)(n0 + rb + srow) * 1024 + k0 + csw, &Bs[rb * 64]);
        }
        __syncthreads();

        short8 aF[4][2], bF[4][2];
#pragma unroll
        for (int mi = 0; mi < 4; ++mi) {
            const int ro = (wm * 64 + mi * 16 + (l & 15)) * 64;
            aF[mi][0] = *(const short8*)&As[ro + kx0];
            aF[mi][1] = *(const short8*)&As[ro + kx1];
        }
#pragma unroll
        for (int ni = 0; ni < 4; ++ni) {
            const int ro = (wn * 64 + ni * 16 + (l & 15)) * 64;
            bF[ni][0] = *(const short8*)&Bs[ro + kx0];
            bF[ni][1] = *(const short8*)&Bs[ro + kx1];
        }
#pragma unroll
        for (int mi = 0; mi < 4; ++mi)
#pragma unroll
            for (int ni = 0; ni < 4; ++ni) {
                acc[mi][ni] = __builtin_amdgcn_mfma_f32_16x16x32_bf16(
                    aF[mi][0], bF[ni][0], acc[mi][ni], 0, 0, 0);
                acc[mi][ni] = __builtin_amdgcn_mfma_f32_16x16x32_bf16(
                    aF[mi][1], bF[ni][1], acc[mi][ni], 0, 0, 0);
            }
        __syncthreads();
    }

    ushort* Cz = Cp + (size_t)blockIdx.z * M * N;
#pragma unroll
    for (int ni = 0; ni < 4; ++ni) {
        const int col = n0 + wn * 64 + ni * 16 + (l & 15);
#pragma unroll
        for (int mi = 0; mi < 4; ++mi) {
            const int row = m0 + wm * 64 + mi * 16 + ((l >> 4) << 2);
#pragma unroll
            for (int r = 0; r < 4; ++r)
                Cz[(size_t)(row + r) * N + col] = f2bf(acc[mi][ni][r]);
        }
    }
}

// ---------------------------------------------------------------------------
__global__ __launch_bounds__(256) void reduce_hq_b_kernel(
    const ushort* __restrict__ part, const float* __restrict__ bias, float* __restrict__ hq)
{
    const int i = blockIdx.x * 256 + threadIdx.x;   // < 1024*512
    float s = bias[i & 511];
#pragma unroll
    for (int z = 0; z < 8; ++z) s += bf2f(part[(size_t)z * 524288 + i]);
    hq[i] = s;
}

__global__ __launch_bounds__(256) void reduce_gate_b_kernel(
    const ushort* __restrict__ part, const float* __restrict__ bias,
    const float* __restrict__ pos, ushort* __restrict__ gpb)
{
    const int i = blockIdx.x * 256 + threadIdx.x;   // < 1024*1024
    float s = bias[i & 1023];
#pragma unroll
    for (int z = 0; z < 4; ++z) s += bf2f(part[(size_t)z * 1048576 + i]);
    const float g = fmaxf(s, 0.f);
    gpb[i] = f2bf(g * pos[i] + pos[i]);
}

// ---------------------------------------------------------------------------
__global__ __launch_bounds__(256) void softmax_af_kernel(
    const float* __restrict__ epart, const ushort* __restrict__ Vb,
    const float* __restrict__ ba2w, ushort* __restrict__ afb)
{
    const int b = blockIdx.x;
    const int tid = threadIdx.x;
    __shared__ float e_raw[LL];
    __shared__ float e_exp[LL];

    if (tid < LL) {
        const float* ep = &epart[(size_t)(b * LL + tid) * 2];
        e_raw[tid] = ba2w[0] + ep[0] + ep[1];
    }
    __syncthreads();
    float mx = -1e30f;
#pragma unroll
    for (int ll = 0; ll < LL; ++ll) mx = fmaxf(mx, e_raw[ll]);
    if (tid < LL) e_exp[tid] = __expf(e_raw[tid] - mx);
    __syncthreads();
    float sum = 0.f;
#pragma unroll
    for (int ll = 0; ll < LL; ++ll) sum += e_exp[ll];
    const float inv = 1.f / sum;

    const int r4 = tid * 4;
    const ushort* vp = &Vb[(size_t)b * LL * RR + r4];
    float a0 = 0.f, a1 = 0.f, a2 = 0.f, a3 = 0.f;
#pragma unroll 8
    for (int ll = 0; ll < LL; ++ll) {
        ushort4 v = *(const ushort4*)&vp[(size_t)ll * RR];
        const float wgt = e_exp[ll];
        a0 += wgt * bf2f(v.x); a1 += wgt * bf2f(v.y);
        a2 += wgt * bf2f(v.z); a3 += wgt * bf2f(v.w);
    }
    ushort* op = &afb[(size_t)b * RR + r4];
    op[0] = f2bf(a0 * inv); op[1] = f2bf(a1 * inv);
    op[2] = f2bf(a2 * inv); op[3] = f2bf(a3 * inv);
}

// ---------------------------------------------------------------------------
__global__ __launch_bounds__(256) void lstm_finishb_kernel(
    const ushort* __restrict__ part,
    const float* __restrict__ bi, const float* __restrict__ ba, const float* __restrict__ bh,
    const float* __restrict__ c_in, const float* __restrict__ h_in, const float* __restrict__ mask,
    float* __restrict__ h_out, float* __restrict__ h_out2,
    float* __restrict__ c_out, ushort* __restrict__ h_bf)
{
    const int i = blockIdx.x * 256 + threadIdx.x;  // [0, B*R)
    const int b = i >> 10;
    const int r = i & 1023;
    float sg[4];
#pragma unroll
    for (int g = 0; g < 4; ++g) {
        const int gr = g * 1024 + r;
        float s = bi[gr] + ba[gr] + bh[gr];
#pragma unroll
        for (int z = 0; z < 4; ++z)
            s += bf2f(part[(size_t)z * 4194304 + (size_t)b * 4096 + gr]);
        sg[g] = s;
    }
    const float ig = fsigmoid(sg[0]);
    const float fg = fsigmoid(sg[1]);
    const float og = fsigmoid(sg[2]);
    const float gt = ftanh(sg[3]);
    const float m = mask[b];
    const float c = c_in[i];
    float cn = fg * c + ig * gt;
    cn = cn * m + c * (1.f - m);
    const float h = h_in[i];
    float hn = og * ftanh(cn);
    hn = hn * m + h * (1.f - m);
    h_out[i] = hn;
    if (h_out2) h_out2[i] = hn;
    c_out[i] = cn;
    if (h_bf) h_bf[i] = f2bf(hn);
}

extern "C" void kernel_launch(void* const* d_in, const int* in_sizes, int n_in,
                              void* d_out, int out_size, void* d_ws, size_t ws_size,
                              hipStream_t stream) {
    const float* xt   = (const float*)d_in[0];
    const float* mask = (const float*)d_in[1];
    const float* V    = (const float*)d_in[2];
    const float* pos  = (const float*)d_in[3];
    const float* h1   = (const float*)d_in[4];
    const float* c1   = (const float*)d_in[5];
    const float* h2   = (const float*)d_in[6];
    const float* c2   = (const float*)d_in[7];
    const float* Wg   = (const float*)d_in[8];
    const float* bg   = (const float*)d_in[9];
    const float* Wi1  = (const float*)d_in[10];
    const float* bi1  = (const float*)d_in[11];
    const float* Wa1  = (const float*)d_in[12];
    const float* ba1  = (const float*)d_in[13];
    const float* Wh1  = (const float*)d_in[14];
    const float* bh1  = (const float*)d_in[15];
    const float* Wi2  = (const float*)d_in[16];
    const float* bi2  = (const float*)d_in[17];
    const float* Wa2  = (const float*)d_in[18];
    const float* ba2  = (const float*)d_in[19];
    const float* Wh2  = (const float*)d_in[20];
    const float* bh2  = (const float*)d_in[21];
    const float* Wv2a = (const float*)d_in[22];
    const float* bv2a = (const float*)d_in[23];
    const float* Wh2a = (const float*)d_in[24];
    const float* bh2a = (const float*)d_in[25];
    const float* Wa2w = (const float*)d_in[26];
    const float* ba2w = (const float*)d_in[27];

    float* out = (float*)d_out;
    float* out2  = out;
    float* out1  = out + (size_t)BB * RR;
    float* c1n   = out + 2 * (size_t)BB * RR;
    float* out2b = out + 3 * (size_t)BB * RR;
    float* c2n   = out + 4 * (size_t)BB * RR;

    // ---- workspace ----
    ushort* wsu = (ushort*)d_ws;
    size_t o = 0;
    ushort* Vb     = wsu + o; o += (size_t)40960 * 1024;   // 84 MB
    ushort* Wh2aT0 = wsu + o; o += (size_t)512 * 1024;
    ushort* Wh2aT1 = wsu + o; o += (size_t)512 * 1024;
    ushort* WgT    = wsu + o; o += (size_t)1024 * 1024;
    ushort* Wv2aT  = wsu + o; o += (size_t)512 * 1024;
    ushort* Wi1T   = wsu + o; o += (size_t)4096 * 1024;
    ushort* Wa1T   = wsu + o; o += (size_t)4096 * 1024;
    ushort* Wh1T   = wsu + o; o += (size_t)4096 * 1024;
    ushort* Wi2T   = wsu + o; o += (size_t)4096 * 1024;
    ushort* Wa2T   = wsu + o; o += (size_t)4096 * 1024;
    ushort* Wh2T   = wsu + o; o += (size_t)4096 * 1024;
    ushort* xtb    = wsu + o; o += (size_t)1024 * 1024;
    ushort* h1b    = wsu + o; o += (size_t)1024 * 1024;
    ushort* h2b    = wsu + o; o += (size_t)1024 * 1024;
    ushort* gpb    = wsu + o; o += (size_t)1024 * 1024;
    ushort* afb    = wsu + o; o += (size_t)1024 * 1024;
    ushort* out1b  = wsu + o; o += (size_t)1024 * 1024;
    ushort* partSb = wsu + o; o += (size_t)8 * 1024 * 512; // hq x8 / gate x4 bf16 partials
    float* wsf    = (float*)(wsu + o);
    float* hqf    = wsf;                   // 524288
    float* epart  = hqf + 524288;          // 40960*2
    // LSTM bf16 partials (4 x 1024 x 4096 ushort = 32 MB) alias Vb (dead after softmax_af)
    ushort* partKb = Vb;

    const dim3 blk(256);
    const dim3 blk8(512);

    // ---- conversion / transpose passes ----
    conv_bf16_kernel<<<dim3(20480), blk, 0, stream>>>(V, Vb, 5242880);
    {
        CP3 p; p.in[0] = xt; p.in[1] = h1; p.in[2] = h2;
        p.out[0] = xtb; p.out[1] = h1b; p.out[2] = h2b;
        conv_bf16_batch3_kernel<<<dim3(512, 3), blk, 0, stream>>>(p, 131072);
    }
    {
        TP6 p;
        p.in[0] = Wi1; p.in[1] = Wa1; p.in[2] = Wh1;
        p.in[3] = Wi2; p.in[4] = Wa2; p.in[5] = Wh2;
        p.out[0] = Wi1T; p.out[1] = Wa1T; p.out[2] = Wh1T;
        p.out[3] = Wi2T; p.out[4] = Wa2T; p.out[5] = Wh2T;
        for (int z = 0; z < 6; ++z) p.N[z] = 4096;
        transpose_conv_kernel<<<dim3(64, 16, 6), blk, 0, stream>>>(p);
    }
    {
        TP6 p;
        p.in[0] = Wh2a; p.in[1] = Wh2a + (size_t)1024 * 512;
        p.in[2] = Wg;   p.in[3] = Wv2a;
        p.out[0] = Wh2aT0; p.out[1] = Wh2aT1; p.out[2] = WgT; p.out[3] = Wv2aT;
        p.N[0] = 512; p.N[1] = 512; p.N[2] = 1024; p.N[3] = 512;
        p.in[4] = nullptr; p.in[5] = nullptr; p.out[4] = nullptr; p.out[5] = nullptr;
        p.N[4] = 0; p.N[5] = 0;
        transpose_conv_kernel<<<dim3(16, 16, 4), blk, 0, stream>>>(p);
    }

    // ---- hq = [h1,h2] @ Wh2a (split-K x8, bf16 partials) + bias reduce ----
    gemm_gl<2, 8><<<dim3(4, 8, 8), blk, 0, stream>>>(
        h1b, h2b, nullptr, Wh2aT0, Wh2aT1, nullptr, partSb, 1024, 512);
    reduce_hq_b_kernel<<<dim3(2048), blk, 0, stream>>>(partSb, bh2a, hqf);

    // ---- gate: xt @ Wg (split-K x4, bf16 partials), relu*pos+pos -> bf16 ----
    gemm_gl<1, 4><<<dim3(8, 8, 4), blk, 0, stream>>>(
        xtb, nullptr, nullptr, WgT, nullptr, nullptr, partSb, 1024, 1024);
    reduce_gate_b_kernel<<<dim3(4096), blk, 0, stream>>>(partSb, bg, pos, gpb);

    // ---- attention scores: 8-phase Vb @ Wv2a, fused tanh-reduce -> epart ----
    gemm8p<1, 16, 2><<<dim3(320), blk8, 0, stream>>>(
        Vb, nullptr, nullptr, Wv2aT, nullptr, nullptr,
        nullptr, 40960, 512, hqf, bv2a, Wa2w, epart);
    softmax_af_kernel<<<dim3(BB), blk, 0, stream>>>(epart, Vb, ba2w, afb);

    // ---- LSTM layer 1 (8-phase, split-K x4 over fused K = xt|gp|h1) ----
    gemm8p<3, 12, 3><<<dim3(4, 16, 4), blk8, 0, stream>>>(
        xtb, gpb, h1b, Wi1T, Wa1T, Wh1T,
        partKb, 1024, 4096, nullptr, nullptr, nullptr, nullptr);
    lstm_finishb_kernel<<<dim3(4096), blk, 0, stream>>>(
        partKb, bi1, ba1, bh1, c1, h1, mask, out1, nullptr, c1n, out1b);

    // ---- LSTM layer 2 (8-phase, split-K x4 over fused K = out1|af|h2) ----
    gemm8p<3, 12, 3><<<dim3(4, 16, 4), blk8, 0, stream>>>(
        out1b, afb, h2b, Wi2T, Wa2T, Wh2T,
        partKb, 1024, 4096, nullptr, nullptr, nullptr, nullptr);
    lstm_finishb_kernel<<<dim3(4096), blk, 0, stream>>>(
        partKb, bi2, ba2, bh2, c2, h2, mask, out2, out2b, c2n, nullptr);
}

// Round 10
// 366.628 us; speedup vs baseline: 1.0955x; 1.0955x over previous
//
#include <hip/hip_runtime.h>
#include <math.h>

#define BB 1024
#define LL 40
#define RR 1024

using short8 = __attribute__((ext_vector_type(8))) short;
using us8    = __attribute__((ext_vector_type(8))) unsigned short;
using f32x4  = __attribute__((ext_vector_type(4))) float;

__device__ __forceinline__ ushort f2bf(float f) {
    union { float f; unsigned u; } a; a.f = f;
    unsigned r = a.u + 0x7fffu + ((a.u >> 16) & 1u);  // RNE
    return (ushort)(r >> 16);
}
__device__ __forceinline__ float bf2f(ushort u) {
    union { unsigned u; float f; } a; a.u = ((unsigned)u) << 16;
    return a.f;
}
__device__ __forceinline__ float ftanh(float x) {
    float cx = fminf(fmaxf(x, -15.f), 15.f);
    float e = __expf(2.f * cx);
    return (e - 1.f) / (e + 1.f);
}
__device__ __forceinline__ float fsigmoid(float x) {
    float cx = fminf(fmaxf(x, -30.f), 30.f);
    return 1.f / (1.f + __expf(-cx));
}

__device__ __forceinline__ void gll16(const ushort* g, ushort* l) {
    __builtin_amdgcn_global_load_lds(
        (const __attribute__((address_space(1))) void*)g,
        (__attribute__((address_space(3))) void*)l,
        16, 0, 0);
}

// ---------------------------------------------------------------------------
__global__ __launch_bounds__(256) void conv_bf16_kernel(
    const float* __restrict__ src, ushort* __restrict__ dst, int n8)
{
    const int i = blockIdx.x * 256 + threadIdx.x;
    if (i >= n8) return;
    const float4* s4 = (const float4*)(src + (size_t)i * 8);
    float4 x = s4[0], y = s4[1];
    us8 v;
    v[0] = f2bf(x.x); v[1] = f2bf(x.y); v[2] = f2bf(x.z); v[3] = f2bf(x.w);
    v[4] = f2bf(y.x); v[5] = f2bf(y.y); v[6] = f2bf(y.z); v[7] = f2bf(y.w);
    ((us8*)dst)[i] = v;
}

struct CP3 { const float* in[3]; ushort* out[3]; };
__global__ __launch_bounds__(256) void conv_bf16_batch3_kernel(CP3 p, int n8)
{
    const int z = blockIdx.y;
    const int i = blockIdx.x * 256 + threadIdx.x;
    if (i >= n8) return;
    const float4* s4 = (const float4*)(p.in[z] + (size_t)i * 8);
    float4 x = s4[0], y = s4[1];
    us8 v;
    v[0] = f2bf(x.x); v[1] = f2bf(x.y); v[2] = f2bf(x.z); v[3] = f2bf(x.w);
    v[4] = f2bf(y.x); v[5] = f2bf(y.y); v[6] = f2bf(y.z); v[7] = f2bf(y.w);
    ((us8*)p.out[z])[i] = v;
}

struct TP6 { const float* in[6]; ushort* out[6]; int N[6]; };
__global__ __launch_bounds__(256) void transpose_conv_kernel(TP6 p)
{
    const int z = blockIdx.z;
    const int Nn = p.N[z];
    const int n0 = blockIdx.x * 64;
    if (n0 >= Nn) return;
    const int k0 = blockIdx.y * 64;
    const float* in = p.in[z];
    ushort* out = p.out[z];

    __shared__ float tile[64][65];
    const int t = threadIdx.x;
    const int tx = t & 63, ty = t >> 6;
#pragma unroll
    for (int r = 0; r < 16; ++r) {
        const int row = ty * 16 + r;
        tile[row][tx] = in[(size_t)(k0 + row) * Nn + n0 + tx];
    }
    __syncthreads();
    const int n = t >> 2, kq = t & 3;
    us8 v0, v1;
#pragma unroll
    for (int j = 0; j < 8; ++j) v0[j] = f2bf(tile[kq * 16 + j][n]);
#pragma unroll
    for (int j = 0; j < 8; ++j) v1[j] = f2bf(tile[kq * 16 + 8 + j][n]);
    ushort* op = out + (size_t)(n0 + n) * 1024 + k0 + kq * 16;
    *(us8*)op = v0;
    *((us8*)op + 1) = v1;
}

// ---------------------------------------------------------------------------
// 128x128 BK=32 4-wave GEMM, double-buffered LDS (2 x 8 KB/operand = 32 KB),
// counted-vmcnt prefetch (T4): issue tile t+1's 4 loads/thread, wait vmcnt(4)
// (retires exactly tile t per-wave), barrier -> buffer resident; compute;
// barrier -> safe to restage. Pair-swizzle LDS layout:
//   LDS[row][c] = global chunk (c ^ ((row>>1)&3)), chunks of 8 elems (16B)
// -> 2 lanes/bank on ds_read_b128 (free) with linear gll16 destinations.
// A_p bf16 [M][1024]; W_p bf16 [N][1024] (pre-transposed). C = sum A_p @ W_p^T.
// EPI: 2 = attn tanh-reduce -> epart[row*4+bx]; 3 = bf16 split-K partial.
// ---------------------------------------------------------------------------
template <int NP, int SK, int EPI>
__global__ __launch_bounds__(256) void gemm_db(
    const ushort* __restrict__ A0, const ushort* __restrict__ A1, const ushort* __restrict__ A2,
    const ushort* __restrict__ W0, const ushort* __restrict__ W1, const ushort* __restrict__ W2,
    ushort* __restrict__ Cp, int M, int N,
    const float* __restrict__ hq, const float* __restrict__ bv2a,
    const float* __restrict__ Wa2w, float* __restrict__ epart)
{
    __shared__ ushort As[2][128 * 32];   // 2 x 8 KB
    __shared__ ushort Bs[2][128 * 32];   // 2 x 8 KB

    const int t = threadIdx.x, l = t & 63, w = t >> 6;
    const int wm = w >> 1, wn = w & 1;

    int bx, by;
    if constexpr (EPI == 2) {
        // XCD-chunked bijective swizzle: nwg = 4*320 = 1280 = 8*160
        const int lin = blockIdx.y * gridDim.x + blockIdx.x;
        const int swz = (lin & 7) * 160 + (lin >> 3);
        bx = swz & 3; by = swz >> 2;
    } else { bx = blockIdx.x; by = blockIdx.y; }
    const int m0 = by * 128, n0 = bx * 128;

    // staging: per wave 2 gll16 per operand; instr j covers 16 rows rb=j*64+w*16
    // lane l -> row rb + (l>>2), dest chunk (l&3) [linear], source chunk
    // (l&3) ^ ((row>>1)&3) = (l&3) ^ ((l>>3)&3)   (rb is a multiple of 8)
    const int srow  = l >> 2;
    const int schnk = ((l & 3) ^ ((l >> 3) & 3)) * 8;

    // fragment read offsets (loop-invariant): row = base+mi*16+(l&15),
    // k-chunk g = l>>4, LDS chunk = g ^ ((row>>1)&3) = g ^ ((l>>1)&3)
    int aoff[4], boff[4];
#pragma unroll
    for (int mi = 0; mi < 4; ++mi)
        aoff[mi] = (wm * 64 + mi * 16 + (l & 15)) * 32 + (((l >> 4) ^ ((l >> 1) & 3)) * 8);
#pragma unroll
    for (int ni = 0; ni < 4; ++ni)
        boff[ni] = (wn * 64 + ni * 16 + (l & 15)) * 32 + (((l >> 4) ^ ((l >> 1) & 3)) * 8);

    f32x4 acc[4][4];
#pragma unroll
    for (int i = 0; i < 4; ++i)
#pragma unroll
        for (int j = 0; j < 4; ++j) acc[i][j] = (f32x4){0.f, 0.f, 0.f, 0.f};

    const int total = NP * 32;           // K-steps of 32
    const int per   = total / SK;
    const int s0v   = blockIdx.z * per;
    const int sEnd  = s0v + per;

    auto stage = [&](int s, int buf) {   // 4 gll16 per thread
        const int p  = (NP == 1) ? 0 : (s >> 5);
        const int k0 = (s & 31) << 5;
        const ushort* Ap = (p == 0) ? A0 : ((p == 1) ? A1 : A2);
        const ushort* Wp = (p == 0) ? W0 : ((p == 1) ? W1 : W2);
#pragma unroll
        for (int j = 0; j < 2; ++j) {
            const int rb = j * 64 + w * 16;
            gll16(Ap + (size_t)(m0 + rb + srow) * 1024 + k0 + schnk, &As[buf][rb * 32]);
            gll16(Wp + (size_t)(n0 + rb + srow) * 1024 + k0 + schnk, &Bs[buf][rb * 32]);
        }
    };

    stage(s0v, 0);                        // prologue: 4 loads/thread in flight
    int cur = 0;
    for (int s = s0v; s < sEnd; ++s) {
        const bool pf = (s + 1 < sEnd);
        if (pf) {
            stage(s + 1, cur ^ 1);        // up to 8 outstanding
            asm volatile("s_waitcnt vmcnt(4)" ::: "memory");   // retire tile s
        } else {
            asm volatile("s_waitcnt vmcnt(0)" ::: "memory");
        }
        __builtin_amdgcn_s_barrier();     // buffer cur resident for all waves
        asm volatile("" ::: "memory");

        short8 aF[4], bF[4];
#pragma unroll
        for (int mi = 0; mi < 4; ++mi) aF[mi] = *(const short8*)&As[cur][aoff[mi]];
#pragma unroll
        for (int ni = 0; ni < 4; ++ni) bF[ni] = *(const short8*)&Bs[cur][boff[ni]];
#pragma unroll
        for (int mi = 0; mi < 4; ++mi)
#pragma unroll
            for (int ni = 0; ni < 4; ++ni)
                acc[mi][ni] = __builtin_amdgcn_mfma_f32_16x16x32_bf16(
                    aF[mi], bF[ni], acc[mi][ni], 0, 0, 0);

        asm volatile("" ::: "memory");
        __builtin_amdgcn_s_barrier();     // all waves done reading cur
        asm volatile("" ::: "memory");
        cur ^= 1;
    }

    if constexpr (EPI == 3) {
        ushort* Cz = Cp + (size_t)blockIdx.z * M * N;
#pragma unroll
        for (int ni = 0; ni < 4; ++ni) {
            const int col = n0 + wn * 64 + ni * 16 + (l & 15);
#pragma unroll
            for (int mi = 0; mi < 4; ++mi) {
                const int row = m0 + wm * 64 + mi * 16 + ((l >> 4) << 2);
#pragma unroll
                for (int r = 0; r < 4; ++r)
                    Cz[(size_t)(row + r) * N + col] = f2bf(acc[mi][ni][r]);
            }
        }
    } else if constexpr (EPI == 2) {
        float* red = (float*)&As[0][0];    // [128][2]
        float wa[4], bv[4];
        int coln[4];
#pragma unroll
        for (int ni = 0; ni < 4; ++ni) {
            coln[ni] = n0 + wn * 64 + ni * 16 + (l & 15);
            wa[ni] = Wa2w[coln[ni]];
            bv[ni] = bv2a[coln[ni]];
        }
#pragma unroll
        for (int mi = 0; mi < 4; ++mi) {
            const int rowl = wm * 64 + mi * 16 + ((l >> 4) << 2);
#pragma unroll
            for (int r = 0; r < 4; ++r) {
                const int row = m0 + rowl + r;
                const int b = row / LL;
                float v = 0.f;
#pragma unroll
                for (int ni = 0; ni < 4; ++ni) {
                    float x = acc[mi][ni][r] + hq[(size_t)b * 512 + coln[ni]] + bv[ni];
                    v += ftanh(x) * wa[ni];
                }
                v += __shfl_xor(v, 1);
                v += __shfl_xor(v, 2);
                v += __shfl_xor(v, 4);
                v += __shfl_xor(v, 8);
                if ((l & 15) == 0) red[(rowl + r) * 2 + wn] = v;
            }
        }
        __syncthreads();
        if (t < 128)
            epart[(size_t)(m0 + t) * 4 + bx] = red[t * 2] + red[t * 2 + 1];
    }
}

// ---------------------------------------------------------------------------
__global__ __launch_bounds__(256) void reduce_hq_b_kernel(
    const ushort* __restrict__ part, const float* __restrict__ bias, float* __restrict__ hq)
{
    const int i = blockIdx.x * 256 + threadIdx.x;   // < 1024*512
    float s = bias[i & 511];
#pragma unroll
    for (int z = 0; z < 8; ++z) s += bf2f(part[(size_t)z * 524288 + i]);
    hq[i] = s;
}

__global__ __launch_bounds__(256) void reduce_gate_b_kernel(
    const ushort* __restrict__ part, const float* __restrict__ bias,
    const float* __restrict__ pos, ushort* __restrict__ gpb)
{
    const int i = blockIdx.x * 256 + threadIdx.x;   // < 1024*1024
    float s = bias[i & 1023];
#pragma unroll
    for (int z = 0; z < 4; ++z) s += bf2f(part[(size_t)z * 1048576 + i]);
    const float g = fmaxf(s, 0.f);
    gpb[i] = f2bf(g * pos[i] + pos[i]);
}

// ---------------------------------------------------------------------------
__global__ __launch_bounds__(256) void softmax_af_kernel(
    const float* __restrict__ epart, const ushort* __restrict__ Vb,
    const float* __restrict__ ba2w, ushort* __restrict__ afb)
{
    const int b = blockIdx.x;
    const int tid = threadIdx.x;
    __shared__ float e_raw[LL];
    __shared__ float e_exp[LL];

    if (tid < LL) {
        const float* ep = &epart[(size_t)(b * LL + tid) * 4];
        float e = ba2w[0];
#pragma unroll
        for (int c = 0; c < 4; ++c) e += ep[c];
        e_raw[tid] = e;
    }
    __syncthreads();
    float mx = -1e30f;
#pragma unroll
    for (int ll = 0; ll < LL; ++ll) mx = fmaxf(mx, e_raw[ll]);
    if (tid < LL) e_exp[tid] = __expf(e_raw[tid] - mx);
    __syncthreads();
    float sum = 0.f;
#pragma unroll
    for (int ll = 0; ll < LL; ++ll) sum += e_exp[ll];
    const float inv = 1.f / sum;

    const int r4 = tid * 4;
    const ushort* vp = &Vb[(size_t)b * LL * RR + r4];
    float a0 = 0.f, a1 = 0.f, a2 = 0.f, a3 = 0.f;
#pragma unroll 8
    for (int ll = 0; ll < LL; ++ll) {
        ushort4 v = *(const ushort4*)&vp[(size_t)ll * RR];
        const float wgt = e_exp[ll];
        a0 += wgt * bf2f(v.x); a1 += wgt * bf2f(v.y);
        a2 += wgt * bf2f(v.z); a3 += wgt * bf2f(v.w);
    }
    ushort* op = &afb[(size_t)b * RR + r4];
    op[0] = f2bf(a0 * inv); op[1] = f2bf(a1 * inv);
    op[2] = f2bf(a2 * inv); op[3] = f2bf(a3 * inv);
}

// ---------------------------------------------------------------------------
__global__ __launch_bounds__(256) void lstm_finishb_kernel(
    const ushort* __restrict__ part,
    const float* __restrict__ bi, const float* __restrict__ ba, const float* __restrict__ bh,
    const float* __restrict__ c_in, const float* __restrict__ h_in, const float* __restrict__ mask,
    float* __restrict__ h_out, float* __restrict__ h_out2,
    float* __restrict__ c_out, ushort* __restrict__ h_bf)
{
    const int i = blockIdx.x * 256 + threadIdx.x;  // [0, B*R)
    const int b = i >> 10;
    const int r = i & 1023;
    float sg[4];
#pragma unroll
    for (int g = 0; g < 4; ++g) {
        const int gr = g * 1024 + r;
        float s = bi[gr] + ba[gr] + bh[gr];
#pragma unroll
        for (int z = 0; z < 4; ++z)
            s += bf2f(part[(size_t)z * 4194304 + (size_t)b * 4096 + gr]);
        sg[g] = s;
    }
    const float ig = fsigmoid(sg[0]);
    const float fg = fsigmoid(sg[1]);
    const float og = fsigmoid(sg[2]);
    const float gt = ftanh(sg[3]);
    const float m = mask[b];
    const float c = c_in[i];
    float cn = fg * c + ig * gt;
    cn = cn * m + c * (1.f - m);
    const float h = h_in[i];
    float hn = og * ftanh(cn);
    hn = hn * m + h * (1.f - m);
    h_out[i] = hn;
    if (h_out2) h_out2[i] = hn;
    c_out[i] = cn;
    if (h_bf) h_bf[i] = f2bf(hn);
}

extern "C" void kernel_launch(void* const* d_in, const int* in_sizes, int n_in,
                              void* d_out, int out_size, void* d_ws, size_t ws_size,
                              hipStream_t stream) {
    const float* xt   = (const float*)d_in[0];
    const float* mask = (const float*)d_in[1];
    const float* V    = (const float*)d_in[2];
    const float* pos  = (const float*)d_in[3];
    const float* h1   = (const float*)d_in[4];
    const float* c1   = (const float*)d_in[5];
    const float* h2   = (const float*)d_in[6];
    const float* c2   = (const float*)d_in[7];
    const float* Wg   = (const float*)d_in[8];
    const float* bg   = (const float*)d_in[9];
    const float* Wi1  = (const float*)d_in[10];
    const float* bi1  = (const float*)d_in[11];
    const float* Wa1  = (const float*)d_in[12];
    const float* ba1  = (const float*)d_in[13];
    const float* Wh1  = (const float*)d_in[14];
    const float* bh1  = (const float*)d_in[15];
    const float* Wi2  = (const float*)d_in[16];
    const float* bi2  = (const float*)d_in[17];
    const float* Wa2  = (const float*)d_in[18];
    const float* ba2  = (const float*)d_in[19];
    const float* Wh2  = (const float*)d_in[20];
    const float* bh2  = (const float*)d_in[21];
    const float* Wv2a = (const float*)d_in[22];
    const float* bv2a = (const float*)d_in[23];
    const float* Wh2a = (const float*)d_in[24];
    const float* bh2a = (const float*)d_in[25];
    const float* Wa2w = (const float*)d_in[26];
    const float* ba2w = (const float*)d_in[27];

    float* out = (float*)d_out;
    float* out2  = out;
    float* out1  = out + (size_t)BB * RR;
    float* c1n   = out + 2 * (size_t)BB * RR;
    float* out2b = out + 3 * (size_t)BB * RR;
    float* c2n   = out + 4 * (size_t)BB * RR;

    // ---- workspace ----
    ushort* wsu = (ushort*)d_ws;
    size_t o = 0;
    ushort* Vb     = wsu + o; o += (size_t)40960 * 1024;   // 84 MB
    ushort* Wh2aT0 = wsu + o; o += (size_t)512 * 1024;
    ushort* Wh2aT1 = wsu + o; o += (size_t)512 * 1024;
    ushort* WgT    = wsu + o; o += (size_t)1024 * 1024;
    ushort* Wv2aT  = wsu + o; o += (size_t)512 * 1024;
    ushort* Wi1T   = wsu + o; o += (size_t)4096 * 1024;
    ushort* Wa1T   = wsu + o; o += (size_t)4096 * 1024;
    ushort* Wh1T   = wsu + o; o += (size_t)4096 * 1024;
    ushort* Wi2T   = wsu + o; o += (size_t)4096 * 1024;
    ushort* Wa2T   = wsu + o; o += (size_t)4096 * 1024;
    ushort* Wh2T   = wsu + o; o += (size_t)4096 * 1024;
    ushort* xtb    = wsu + o; o += (size_t)1024 * 1024;
    ushort* h1b    = wsu + o; o += (size_t)1024 * 1024;
    ushort* h2b    = wsu + o; o += (size_t)1024 * 1024;
    ushort* gpb    = wsu + o; o += (size_t)1024 * 1024;
    ushort* afb    = wsu + o; o += (size_t)1024 * 1024;
    ushort* out1b  = wsu + o; o += (size_t)1024 * 1024;
    ushort* partSb = wsu + o; o += (size_t)8 * 1024 * 512; // hq x8 / gate x4 bf16 partials
    float* wsf    = (float*)(wsu + o);
    float* hqf    = wsf;                   // 524288
    float* epart  = hqf + 524288;          // 40960*4
    // LSTM bf16 partials (4 x 1024 x 4096 ushort = 32 MB) alias Vb (dead after softmax_af)
    ushort* partKb = Vb;

    const dim3 blk(256);

    // ---- conversion / transpose passes ----
    conv_bf16_kernel<<<dim3(20480), blk, 0, stream>>>(V, Vb, 5242880);
    {
        CP3 p; p.in[0] = xt; p.in[1] = h1; p.in[2] = h2;
        p.out[0] = xtb; p.out[1] = h1b; p.out[2] = h2b;
        conv_bf16_batch3_kernel<<<dim3(512, 3), blk, 0, stream>>>(p, 131072);
    }
    {
        TP6 p;
        p.in[0] = Wi1; p.in[1] = Wa1; p.in[2] = Wh1;
        p.in[3] = Wi2; p.in[4] = Wa2; p.in[5] = Wh2;
        p.out[0] = Wi1T; p.out[1] = Wa1T; p.out[2] = Wh1T;
        p.out[3] = Wi2T; p.out[4] = Wa2T; p.out[5] = Wh2T;
        for (int z = 0; z < 6; ++z) p.N[z] = 4096;
        transpose_conv_kernel<<<dim3(64, 16, 6), blk, 0, stream>>>(p);
    }
    {
        TP6 p;
        p.in[0] = Wh2a; p.in[1] = Wh2a + (size_t)1024 * 512;
        p.in[2] = Wg;   p.in[3] = Wv2a;
        p.out[0] = Wh2aT0; p.out[1] = Wh2aT1; p.out[2] = WgT; p.out[3] = Wv2aT;
        p.N[0] = 512; p.N[1] = 512; p.N[2] = 1024; p.N[3] = 512;
        p.in[4] = nullptr; p.in[5] = nullptr; p.out[4] = nullptr; p.out[5] = nullptr;
        p.N[4] = 0; p.N[5] = 0;
        transpose_conv_kernel<<<dim3(16, 16, 4), blk, 0, stream>>>(p);
    }

    // ---- hq = [h1,h2] @ Wh2a (split-K x8, bf16 partials) + bias reduce ----
    gemm_db<2, 8, 3><<<dim3(4, 8, 8), blk, 0, stream>>>(
        h1b, h2b, nullptr, Wh2aT0, Wh2aT1, nullptr,
        partSb, 1024, 512, nullptr, nullptr, nullptr, nullptr);
    reduce_hq_b_kernel<<<dim3(2048), blk, 0, stream>>>(partSb, bh2a, hqf);

    // ---- gate: xt @ Wg (split-K x4, bf16 partials), relu*pos+pos -> bf16 ----
    gemm_db<1, 4, 3><<<dim3(8, 8, 4), blk, 0, stream>>>(
        xtb, nullptr, nullptr, WgT, nullptr, nullptr,
        partSb, 1024, 1024, nullptr, nullptr, nullptr, nullptr);
    reduce_gate_b_kernel<<<dim3(4096), blk, 0, stream>>>(partSb, bg, pos, gpb);

    // ---- attention scores: Vb @ Wv2a, fused tanh-reduce -> epart ----
    gemm_db<1, 1, 2><<<dim3(4, 320, 1), blk, 0, stream>>>(
        Vb, nullptr, nullptr, Wv2aT, nullptr, nullptr,
        nullptr, 40960, 512, hqf, bv2a, Wa2w, epart);
    softmax_af_kernel<<<dim3(BB), blk, 0, stream>>>(epart, Vb, ba2w, afb);

    // ---- LSTM layer 1 (split-K x4 over fused K = xt|gp|h1, bf16 partials) ----
    gemm_db<3, 4, 3><<<dim3(32, 8, 4), blk, 0, stream>>>(
        xtb, gpb, h1b, Wi1T, Wa1T, Wh1T,
        partKb, 1024, 4096, nullptr, nullptr, nullptr, nullptr);
    lstm_finishb_kernel<<<dim3(4096), blk, 0, stream>>>(
        partKb, bi1, ba1, bh1, c1, h1, mask, out1, nullptr, c1n, out1b);

    // ---- LSTM layer 2 (split-K x4 over fused K = out1|af|h2) ----
    gemm_db<3, 4, 3><<<dim3(32, 8, 4), blk, 0, stream>>>(
        out1b, afb, h2b, Wi2T, Wa2T, Wh2T,
        partKb, 1024, 4096, nullptr, nullptr, nullptr, nullptr);
    lstm_finishb_kernel<<<dim3(4096), blk, 0, stream>>>(
        partKb, bi2, ba2, bh2, c2, h2, mask, out2, out2b, c2n, nullptr);
}

// Round 11
// 326.718 us; speedup vs baseline: 1.2293x; 1.1222x over previous
//
#include <hip/hip_runtime.h>
#include <math.h>

#define BB 1024
#define LL 40
#define RR 1024

using short8 = __attribute__((ext_vector_type(8))) short;
using us8    = __attribute__((ext_vector_type(8))) unsigned short;
using f32x4  = __attribute__((ext_vector_type(4))) float;

__device__ __forceinline__ ushort f2bf(float f) {
    union { float f; unsigned u; } a; a.f = f;
    unsigned r = a.u + 0x7fffu + ((a.u >> 16) & 1u);  // RNE
    return (ushort)(r >> 16);
}
__device__ __forceinline__ float bf2f(ushort u) {
    union { unsigned u; float f; } a; a.u = ((unsigned)u) << 16;
    return a.f;
}
__device__ __forceinline__ float ftanh(float x) {
    float cx = fminf(fmaxf(x, -15.f), 15.f);
    float e = __expf(2.f * cx);
    return (e - 1.f) / (e + 1.f);
}
__device__ __forceinline__ float fsigmoid(float x) {
    float cx = fminf(fmaxf(x, -30.f), 30.f);
    return 1.f / (1.f + __expf(-cx));
}

__device__ __forceinline__ void gll16(const ushort* g, ushort* l) {
    __builtin_amdgcn_global_load_lds(
        (const __attribute__((address_space(1))) void*)g,
        (__attribute__((address_space(3))) void*)l,
        16, 0, 0);
}

// ---------------------------------------------------------------------------
__global__ __launch_bounds__(256) void conv_bf16_kernel(
    const float* __restrict__ src, ushort* __restrict__ dst, int n8)
{
    const int i = blockIdx.x * 256 + threadIdx.x;
    if (i >= n8) return;
    const float4* s4 = (const float4*)(src + (size_t)i * 8);
    float4 x = s4[0], y = s4[1];
    us8 v;
    v[0] = f2bf(x.x); v[1] = f2bf(x.y); v[2] = f2bf(x.z); v[3] = f2bf(x.w);
    v[4] = f2bf(y.x); v[5] = f2bf(y.y); v[6] = f2bf(y.z); v[7] = f2bf(y.w);
    ((us8*)dst)[i] = v;
}

struct CP3 { const float* in[3]; ushort* out[3]; };
__global__ __launch_bounds__(256) void conv_bf16_batch3_kernel(CP3 p, int n8)
{
    const int z = blockIdx.y;
    const int i = blockIdx.x * 256 + threadIdx.x;
    if (i >= n8) return;
    const float4* s4 = (const float4*)(p.in[z] + (size_t)i * 8);
    float4 x = s4[0], y = s4[1];
    us8 v;
    v[0] = f2bf(x.x); v[1] = f2bf(x.y); v[2] = f2bf(x.z); v[3] = f2bf(x.w);
    v[4] = f2bf(y.x); v[5] = f2bf(y.y); v[6] = f2bf(y.z); v[7] = f2bf(y.w);
    ((us8*)p.out[z])[i] = v;
}

struct TP6 { const float* in[6]; ushort* out[6]; int N[6]; };
__global__ __launch_bounds__(256) void transpose_conv_kernel(TP6 p)
{
    const int z = blockIdx.z;
    const int Nn = p.N[z];
    const int n0 = blockIdx.x * 64;
    if (n0 >= Nn) return;
    const int k0 = blockIdx.y * 64;
    const float* in = p.in[z];
    ushort* out = p.out[z];

    __shared__ float tile[64][65];
    const int t = threadIdx.x;
    const int tx = t & 63, ty = t >> 6;
#pragma unroll
    for (int r = 0; r < 16; ++r) {
        const int row = ty * 16 + r;
        tile[row][tx] = in[(size_t)(k0 + row) * Nn + n0 + tx];
    }
    __syncthreads();
    const int n = t >> 2, kq = t & 3;
    us8 v0, v1;
#pragma unroll
    for (int j = 0; j < 8; ++j) v0[j] = f2bf(tile[kq * 16 + j][n]);
#pragma unroll
    for (int j = 0; j < 8; ++j) v1[j] = f2bf(tile[kq * 16 + 8 + j][n]);
    ushort* op = out + (size_t)(n0 + n) * 1024 + k0 + kq * 16;
    *(us8*)op = v0;
    *((us8*)op + 1) = v1;
}

// ---------------------------------------------------------------------------
// R8-proven 128x128 BK=64 4-wave GEMM (single-buffer, XOR swizzle, 0 bank
// conflicts). For hq/gate/LSTM. bf16 split-K partial store.
// ---------------------------------------------------------------------------
template <int NP, int SK>
__global__ __launch_bounds__(256) void gemm_gl(
    const ushort* __restrict__ A0, const ushort* __restrict__ A1, const ushort* __restrict__ A2,
    const ushort* __restrict__ W0, const ushort* __restrict__ W1, const ushort* __restrict__ W2,
    ushort* __restrict__ Cp, int M, int N)
{
    __shared__ ushort As[128 * 64];
    __shared__ ushort Bs[128 * 64];

    const int t = threadIdx.x, l = t & 63, w = t >> 6;
    const int wm = w >> 1, wn = w & 1;
    const int m0 = blockIdx.y * 128, n0 = blockIdx.x * 128;

    const int srow = l >> 3;
    const int csw  = ((l & 7) ^ (l >> 3)) * 8;
    const int kx0 = ((0 + (l >> 4)) ^ (l & 7)) * 8;
    const int kx1 = ((4 + (l >> 4)) ^ (l & 7)) * 8;

    f32x4 acc[4][4];
#pragma unroll
    for (int i = 0; i < 4; ++i)
#pragma unroll
        for (int j = 0; j < 4; ++j) acc[i][j] = (f32x4){0.f, 0.f, 0.f, 0.f};

    const int total = NP * 16;
    const int per   = total / SK;
    const int s0v   = blockIdx.z * per;
    const int sEnd  = s0v + per;

    for (int s = s0v; s < sEnd; ++s) {
        const int p  = (NP == 1) ? 0 : (s >> 4);
        const int k0 = (s & 15) << 6;
        const ushort* Ap = (p == 0) ? A0 : ((p == 1) ? A1 : A2);
        const ushort* Wp = (p == 0) ? W0 : ((p == 1) ? W1 : W2);
#pragma unroll
        for (int j = 0; j < 4; ++j) {
            const int rb = w * 32 + j * 8;
            gll16(Ap + (size_t)(m0 + rb + srow) * 1024 + k0 + csw, &As[rb * 64]);
            gll16(Wp + (size_t)(n0 + rb + srow) * 1024 + k0 + csw, &Bs[rb * 64]);
        }
        __syncthreads();

        short8 aF[4][2], bF[4][2];
#pragma unroll
        for (int mi = 0; mi < 4; ++mi) {
            const int ro = (wm * 64 + mi * 16 + (l & 15)) * 64;
            aF[mi][0] = *(const short8*)&As[ro + kx0];
            aF[mi][1] = *(const short8*)&As[ro + kx1];
        }
#pragma unroll
        for (int ni = 0; ni < 4; ++ni) {
            const int ro = (wn * 64 + ni * 16 + (l & 15)) * 64;
            bF[ni][0] = *(const short8*)&Bs[ro + kx0];
            bF[ni][1] = *(const short8*)&Bs[ro + kx1];
        }
#pragma unroll
        for (int mi = 0; mi < 4; ++mi)
#pragma unroll
            for (int ni = 0; ni < 4; ++ni) {
                acc[mi][ni] = __builtin_amdgcn_mfma_f32_16x16x32_bf16(
                    aF[mi][0], bF[ni][0], acc[mi][ni], 0, 0, 0);
                acc[mi][ni] = __builtin_amdgcn_mfma_f32_16x16x32_bf16(
                    aF[mi][1], bF[ni][1], acc[mi][ni], 0, 0, 0);
            }
        __syncthreads();
    }

    ushort* Cz = Cp + (size_t)blockIdx.z * M * N;
#pragma unroll
    for (int ni = 0; ni < 4; ++ni) {
        const int col = n0 + wn * 64 + ni * 16 + (l & 15);
#pragma unroll
        for (int mi = 0; mi < 4; ++mi) {
            const int row = m0 + wm * 64 + mi * 16 + ((l >> 4) << 2);
#pragma unroll
            for (int r = 0; r < 4; ++r)
                Cz[(size_t)(row + r) * N + col] = f2bf(acc[mi][ni][r]);
        }
    }
}

// ---------------------------------------------------------------------------
// Attn GEMM: 128x128 BK=32, TRIPLE-buffered ring, prefetch distance 2
// (stage(s+2) -> vmcnt(8) retires tile s). Pair-swizzle LDS (R10-verified,
// 0 bank conflicts). 48 KB LDS -> 3 blocks/CU. Fused tanh*Wa2w epilogue.
// ---------------------------------------------------------------------------
__global__ __launch_bounds__(256) void attn_tri(
    const ushort* __restrict__ A0, const ushort* __restrict__ W0,
    const float* __restrict__ hq, const float* __restrict__ bv2a,
    const float* __restrict__ Wa2w, float* __restrict__ epart)
{
    __shared__ ushort As[3][128 * 32];   // 3 x 8 KB
    __shared__ ushort Bs[3][128 * 32];   // 3 x 8 KB

    const int t = threadIdx.x, l = t & 63, w = t >> 6;
    const int wm = w >> 1, wn = w & 1;

    // XCD-chunked bijective swizzle: nwg = 4*320 = 1280 = 8*160
    const int lin = blockIdx.y * gridDim.x + blockIdx.x;
    const int swz = (lin & 7) * 160 + (lin >> 3);
    const int bx = swz & 3, by = swz >> 2;
    const int m0 = by * 128, n0 = bx * 128;

    const int srow  = l >> 2;
    const int schnk = ((l & 3) ^ ((l >> 3) & 3)) * 8;

    int aoff[4], boff[4];
#pragma unroll
    for (int mi = 0; mi < 4; ++mi)
        aoff[mi] = (wm * 64 + mi * 16 + (l & 15)) * 32 + (((l >> 4) ^ ((l >> 1) & 3)) * 8);
#pragma unroll
    for (int ni = 0; ni < 4; ++ni)
        boff[ni] = (wn * 64 + ni * 16 + (l & 15)) * 32 + (((l >> 4) ^ ((l >> 1) & 3)) * 8);

    f32x4 acc[4][4];
#pragma unroll
    for (int i = 0; i < 4; ++i)
#pragma unroll
        for (int j = 0; j < 4; ++j) acc[i][j] = (f32x4){0.f, 0.f, 0.f, 0.f};

    auto stage = [&](int s, int buf) {   // 4 gll16 per thread
        const int k0 = s << 5;
#pragma unroll
        for (int j = 0; j < 2; ++j) {
            const int rb = j * 64 + w * 16;
            gll16(A0 + (size_t)(m0 + rb + srow) * 1024 + k0 + schnk, &As[buf][rb * 32]);
            gll16(W0 + (size_t)(n0 + rb + srow) * 1024 + k0 + schnk, &Bs[buf][rb * 32]);
        }
    };

    constexpr int NS = 32;               // K-steps of 32 (K = 1024)
    stage(0, 0);
    stage(1, 1);
    for (int s = 0; s < NS; ++s) {
        if (s >= 1 && s + 2 < NS) {
            // all waves done compute(s-1) -> safe to restage buf (s+2)%3
            __builtin_amdgcn_s_barrier();
            asm volatile("" ::: "memory");
        }
        if (s + 2 < NS) {
            stage(s + 2, (s + 2) % 3);   // outstanding: tiles s,s+1,s+2 = 12
            asm volatile("s_waitcnt vmcnt(8)" ::: "memory");   // retire tile s
        } else if (s + 1 < NS) {
            asm volatile("s_waitcnt vmcnt(4)" ::: "memory");
        } else {
            asm volatile("s_waitcnt vmcnt(0)" ::: "memory");
        }
        __builtin_amdgcn_s_barrier();    // tile s resident for all waves
        asm volatile("" ::: "memory");

        const ushort* Ab = &As[s % 3][0];
        const ushort* Bb = &Bs[s % 3][0];
        short8 aF[4], bF[4];
#pragma unroll
        for (int mi = 0; mi < 4; ++mi) aF[mi] = *(const short8*)&Ab[aoff[mi]];
#pragma unroll
        for (int ni = 0; ni < 4; ++ni) bF[ni] = *(const short8*)&Bb[boff[ni]];
#pragma unroll
        for (int mi = 0; mi < 4; ++mi)
#pragma unroll
            for (int ni = 0; ni < 4; ++ni)
                acc[mi][ni] = __builtin_amdgcn_mfma_f32_16x16x32_bf16(
                    aF[mi], bF[ni], acc[mi][ni], 0, 0, 0);
    }

    // ---- fused epilogue: tanh(acc + hq + bv2a) * Wa2w reduced over 128 cols
    __syncthreads();                      // all compute done before LDS reuse
    float* red = (float*)&As[0][0];       // [128][2]
    float wa[4], bv[4];
    int coln[4];
#pragma unroll
    for (int ni = 0; ni < 4; ++ni) {
        coln[ni] = n0 + wn * 64 + ni * 16 + (l & 15);
        wa[ni] = Wa2w[coln[ni]];
        bv[ni] = bv2a[coln[ni]];
    }
#pragma unroll
    for (int mi = 0; mi < 4; ++mi) {
        const int rowl = wm * 64 + mi * 16 + ((l >> 4) << 2);
#pragma unroll
        for (int r = 0; r < 4; ++r) {
            const int row = m0 + rowl + r;
            const int b = row / LL;
            float v = 0.f;
#pragma unroll
            for (int ni = 0; ni < 4; ++ni) {
                float x = acc[mi][ni][r] + hq[(size_t)b * 512 + coln[ni]] + bv[ni];
                v += ftanh(x) * wa[ni];
            }
            v += __shfl_xor(v, 1);
            v += __shfl_xor(v, 2);
            v += __shfl_xor(v, 4);
            v += __shfl_xor(v, 8);
            if ((l & 15) == 0) red[(rowl + r) * 2 + wn] = v;
        }
    }
    __syncthreads();
    if (t < 128)
        epart[(size_t)(m0 + t) * 4 + bx] = red[t * 2] + red[t * 2 + 1];
}

// ---------------------------------------------------------------------------
__global__ __launch_bounds__(256) void reduce_hq_b_kernel(
    const ushort* __restrict__ part, const float* __restrict__ bias, float* __restrict__ hq)
{
    const int i = blockIdx.x * 256 + threadIdx.x;   // < 1024*512
    float s = bias[i & 511];
#pragma unroll
    for (int z = 0; z < 8; ++z) s += bf2f(part[(size_t)z * 524288 + i]);
    hq[i] = s;
}

__global__ __launch_bounds__(256) void reduce_gate_b_kernel(
    const ushort* __restrict__ part, const float* __restrict__ bias,
    const float* __restrict__ pos, ushort* __restrict__ gpb)
{
    const int i = blockIdx.x * 256 + threadIdx.x;   // < 1024*1024
    float s = bias[i & 1023];
#pragma unroll
    for (int z = 0; z < 4; ++z) s += bf2f(part[(size_t)z * 1048576 + i]);
    const float g = fmaxf(s, 0.f);
    gpb[i] = f2bf(g * pos[i] + pos[i]);
}

// ---------------------------------------------------------------------------
__global__ __launch_bounds__(256) void softmax_af_kernel(
    const float* __restrict__ epart, const ushort* __restrict__ Vb,
    const float* __restrict__ ba2w, ushort* __restrict__ afb)
{
    const int b = blockIdx.x;
    const int tid = threadIdx.x;
    __shared__ float e_raw[LL];
    __shared__ float e_exp[LL];

    if (tid < LL) {
        const float* ep = &epart[(size_t)(b * LL + tid) * 4];
        float e = ba2w[0];
#pragma unroll
        for (int c = 0; c < 4; ++c) e += ep[c];
        e_raw[tid] = e;
    }
    __syncthreads();
    float mx = -1e30f;
#pragma unroll
    for (int ll = 0; ll < LL; ++ll) mx = fmaxf(mx, e_raw[ll]);
    if (tid < LL) e_exp[tid] = __expf(e_raw[tid] - mx);
    __syncthreads();
    float sum = 0.f;
#pragma unroll
    for (int ll = 0; ll < LL; ++ll) sum += e_exp[ll];
    const float inv = 1.f / sum;

    const int r4 = tid * 4;
    const ushort* vp = &Vb[(size_t)b * LL * RR + r4];
    float a0 = 0.f, a1 = 0.f, a2 = 0.f, a3 = 0.f;
#pragma unroll 8
    for (int ll = 0; ll < LL; ++ll) {
        ushort4 v = *(const ushort4*)&vp[(size_t)ll * RR];
        const float wgt = e_exp[ll];
        a0 += wgt * bf2f(v.x); a1 += wgt * bf2f(v.y);
        a2 += wgt * bf2f(v.z); a3 += wgt * bf2f(v.w);
    }
    ushort* op = &afb[(size_t)b * RR + r4];
    op[0] = f2bf(a0 * inv); op[1] = f2bf(a1 * inv);
    op[2] = f2bf(a2 * inv); op[3] = f2bf(a3 * inv);
}

// ---------------------------------------------------------------------------
__global__ __launch_bounds__(256) void lstm_finishb_kernel(
    const ushort* __restrict__ part,
    const float* __restrict__ bi, const float* __restrict__ ba, const float* __restrict__ bh,
    const float* __restrict__ c_in, const float* __restrict__ h_in, const float* __restrict__ mask,
    float* __restrict__ h_out, float* __restrict__ h_out2,
    float* __restrict__ c_out, ushort* __restrict__ h_bf)
{
    const int i = blockIdx.x * 256 + threadIdx.x;  // [0, B*R)
    const int b = i >> 10;
    const int r = i & 1023;
    float sg[4];
#pragma unroll
    for (int g = 0; g < 4; ++g) {
        const int gr = g * 1024 + r;
        float s = bi[gr] + ba[gr] + bh[gr];
#pragma unroll
        for (int z = 0; z < 4; ++z)
            s += bf2f(part[(size_t)z * 4194304 + (size_t)b * 4096 + gr]);
        sg[g] = s;
    }
    const float ig = fsigmoid(sg[0]);
    const float fg = fsigmoid(sg[1]);
    const float og = fsigmoid(sg[2]);
    const float gt = ftanh(sg[3]);
    const float m = mask[b];
    const float c = c_in[i];
    float cn = fg * c + ig * gt;
    cn = cn * m + c * (1.f - m);
    const float h = h_in[i];
    float hn = og * ftanh(cn);
    hn = hn * m + h * (1.f - m);
    h_out[i] = hn;
    if (h_out2) h_out2[i] = hn;
    c_out[i] = cn;
    if (h_bf) h_bf[i] = f2bf(hn);
}

extern "C" void kernel_launch(void* const* d_in, const int* in_sizes, int n_in,
                              void* d_out, int out_size, void* d_ws, size_t ws_size,
                              hipStream_t stream) {
    const float* xt   = (const float*)d_in[0];
    const float* mask = (const float*)d_in[1];
    const float* V    = (const float*)d_in[2];
    const float* pos  = (const float*)d_in[3];
    const float* h1   = (const float*)d_in[4];
    const float* c1   = (const float*)d_in[5];
    const float* h2   = (const float*)d_in[6];
    const float* c2   = (const float*)d_in[7];
    const float* Wg   = (const float*)d_in[8];
    const float* bg   = (const float*)d_in[9];
    const float* Wi1  = (const float*)d_in[10];
    const float* bi1  = (const float*)d_in[11];
    const float* Wa1  = (const float*)d_in[12];
    const float* ba1  = (const float*)d_in[13];
    const float* Wh1  = (const float*)d_in[14];
    const float* bh1  = (const float*)d_in[15];
    const float* Wi2  = (const float*)d_in[16];
    const float* bi2  = (const float*)d_in[17];
    const float* Wa2  = (const float*)d_in[18];
    const float* ba2  = (const float*)d_in[19];
    const float* Wh2  = (const float*)d_in[20];
    const float* bh2  = (const float*)d_in[21];
    const float* Wv2a = (const float*)d_in[22];
    const float* bv2a = (const float*)d_in[23];
    const float* Wh2a = (const float*)d_in[24];
    const float* bh2a = (const float*)d_in[25];
    const float* Wa2w = (const float*)d_in[26];
    const float* ba2w = (const float*)d_in[27];

    float* out = (float*)d_out;
    float* out2  = out;
    float* out1  = out + (size_t)BB * RR;
    float* c1n   = out + 2 * (size_t)BB * RR;
    float* out2b = out + 3 * (size_t)BB * RR;
    float* c2n   = out + 4 * (size_t)BB * RR;

    // ---- workspace ----
    ushort* wsu = (ushort*)d_ws;
    size_t o = 0;
    ushort* Vb     = wsu + o; o += (size_t)40960 * 1024;   // 84 MB
    ushort* Wh2aT0 = wsu + o; o += (size_t)512 * 1024;
    ushort* Wh2aT1 = wsu + o; o += (size_t)512 * 1024;
    ushort* WgT    = wsu + o; o += (size_t)1024 * 1024;
    ushort* Wv2aT  = wsu + o; o += (size_t)512 * 1024;
    ushort* Wi1T   = wsu + o; o += (size_t)4096 * 1024;
    ushort* Wa1T   = wsu + o; o += (size_t)4096 * 1024;
    ushort* Wh1T   = wsu + o; o += (size_t)4096 * 1024;
    ushort* Wi2T   = wsu + o; o += (size_t)4096 * 1024;
    ushort* Wa2T   = wsu + o; o += (size_t)4096 * 1024;
    ushort* Wh2T   = wsu + o; o += (size_t)4096 * 1024;
    ushort* xtb    = wsu + o; o += (size_t)1024 * 1024;
    ushort* h1b    = wsu + o; o += (size_t)1024 * 1024;
    ushort* h2b    = wsu + o; o += (size_t)1024 * 1024;
    ushort* gpb    = wsu + o; o += (size_t)1024 * 1024;
    ushort* afb    = wsu + o; o += (size_t)1024 * 1024;
    ushort* out1b  = wsu + o; o += (size_t)1024 * 1024;
    ushort* partSb = wsu + o; o += (size_t)8 * 1024 * 512; // hq x8 / gate x4 bf16 partials
    float* wsf    = (float*)(wsu + o);
    float* hqf    = wsf;                   // 524288
    float* epart  = hqf + 524288;          // 40960*4
    // LSTM bf16 partials (4 x 1024 x 4096 ushort = 32 MB) alias Vb (dead after softmax_af)
    ushort* partKb = Vb;

    const dim3 blk(256);

    // ---- conversion / transpose passes ----
    conv_bf16_kernel<<<dim3(20480), blk, 0, stream>>>(V, Vb, 5242880);
    {
        CP3 p; p.in[0] = xt; p.in[1] = h1; p.in[2] = h2;
        p.out[0] = xtb; p.out[1] = h1b; p.out[2] = h2b;
        conv_bf16_batch3_kernel<<<dim3(512, 3), blk, 0, stream>>>(p, 131072);
    }
    {
        TP6 p;
        p.in[0] = Wi1; p.in[1] = Wa1; p.in[2] = Wh1;
        p.in[3] = Wi2; p.in[4] = Wa2; p.in[5] = Wh2;
        p.out[0] = Wi1T; p.out[1] = Wa1T; p.out[2] = Wh1T;
        p.out[3] = Wi2T; p.out[4] = Wa2T; p.out[5] = Wh2T;
        for (int z = 0; z < 6; ++z) p.N[z] = 4096;
        transpose_conv_kernel<<<dim3(64, 16, 6), blk, 0, stream>>>(p);
    }
    {
        TP6 p;
        p.in[0] = Wh2a; p.in[1] = Wh2a + (size_t)1024 * 512;
        p.in[2] = Wg;   p.in[3] = Wv2a;
        p.out[0] = Wh2aT0; p.out[1] = Wh2aT1; p.out[2] = WgT; p.out[3] = Wv2aT;
        p.N[0] = 512; p.N[1] = 512; p.N[2] = 1024; p.N[3] = 512;
        p.in[4] = nullptr; p.in[5] = nullptr; p.out[4] = nullptr; p.out[5] = nullptr;
        p.N[4] = 0; p.N[5] = 0;
        transpose_conv_kernel<<<dim3(16, 16, 4), blk, 0, stream>>>(p);
    }

    // ---- hq = [h1,h2] @ Wh2a (split-K x8, bf16 partials) + bias reduce ----
    gemm_gl<2, 8><<<dim3(4, 8, 8), blk, 0, stream>>>(
        h1b, h2b, nullptr, Wh2aT0, Wh2aT1, nullptr, partSb, 1024, 512);
    reduce_hq_b_kernel<<<dim3(2048), blk, 0, stream>>>(partSb, bh2a, hqf);

    // ---- gate: xt @ Wg (split-K x4, bf16 partials), relu*pos+pos -> bf16 ----
    gemm_gl<1, 4><<<dim3(8, 8, 4), blk, 0, stream>>>(
        xtb, nullptr, nullptr, WgT, nullptr, nullptr, partSb, 1024, 1024);
    reduce_gate_b_kernel<<<dim3(4096), blk, 0, stream>>>(partSb, bg, pos, gpb);

    // ---- attention scores: tri-buffered Vb @ Wv2a, fused tanh-reduce ----
    attn_tri<<<dim3(4, 320), blk, 0, stream>>>(
        Vb, Wv2aT, hqf, bv2a, Wa2w, epart);
    softmax_af_kernel<<<dim3(BB), blk, 0, stream>>>(epart, Vb, ba2w, afb);

    // ---- LSTM layer 1 (split-K x4 over fused K = xt|gp|h1, bf16 partials) ----
    gemm_gl<3, 4><<<dim3(32, 8, 4), blk, 0, stream>>>(
        xtb, gpb, h1b, Wi1T, Wa1T, Wh1T, partKb, 1024, 4096);
    lstm_finishb_kernel<<<dim3(4096), blk, 0, stream>>>(
        partKb, bi1, ba1, bh1, c1, h1, mask, out1, nullptr, c1n, out1b);

    // ---- LSTM layer 2 (split-K x4 over fused K = out1|af|h2) ----
    gemm_gl<3, 4><<<dim3(32, 8, 4), blk, 0, stream>>>(
        out1b, afb, h2b, Wi2T, Wa2T, Wh2T, partKb, 1024, 4096);
    lstm_finishb_kernel<<<dim3(4096), blk, 0, stream>>>(
        partKb, bi2, ba2, bh2, c2, h2, mask, out2, out2b, c2n, nullptr);
}

// Round 12
// 312.168 us; speedup vs baseline: 1.2866x; 1.0466x over previous
//
#include <hip/hip_runtime.h>
#include <math.h>

#define BB 1024
#define LL 40
#define RR 1024

using short8 = __attribute__((ext_vector_type(8))) short;
using us8    = __attribute__((ext_vector_type(8))) unsigned short;
using f32x4  = __attribute__((ext_vector_type(4))) float;

__device__ __forceinline__ ushort f2bf(float f) {
    union { float f; unsigned u; } a; a.f = f;
    unsigned r = a.u + 0x7fffu + ((a.u >> 16) & 1u);  // RNE
    return (ushort)(r >> 16);
}
__device__ __forceinline__ float bf2f(ushort u) {
    union { unsigned u; float f; } a; a.u = ((unsigned)u) << 16;
    return a.f;
}
__device__ __forceinline__ float ftanh(float x) {
    float cx = fminf(fmaxf(x, -15.f), 15.f);
    float e = __expf(2.f * cx);
    return (e - 1.f) / (e + 1.f);
}
__device__ __forceinline__ float fsigmoid(float x) {
    float cx = fminf(fmaxf(x, -30.f), 30.f);
    return 1.f / (1.f + __expf(-cx));
}

__device__ __forceinline__ void gll16(const ushort* g, ushort* l) {
    __builtin_amdgcn_global_load_lds(
        (const __attribute__((address_space(1))) void*)g,
        (__attribute__((address_space(3))) void*)l,
        16, 0, 0);
}

// ---------------------------------------------------------------------------
__global__ __launch_bounds__(256) void conv_bf16_kernel(
    const float* __restrict__ src, ushort* __restrict__ dst, int n8)
{
    const int i = blockIdx.x * 256 + threadIdx.x;
    if (i >= n8) return;
    const float4* s4 = (const float4*)(src + (size_t)i * 8);
    float4 x = s4[0], y = s4[1];
    us8 v;
    v[0] = f2bf(x.x); v[1] = f2bf(x.y); v[2] = f2bf(x.z); v[3] = f2bf(x.w);
    v[4] = f2bf(y.x); v[5] = f2bf(y.y); v[6] = f2bf(y.z); v[7] = f2bf(y.w);
    ((us8*)dst)[i] = v;
}

struct CP3 { const float* in[3]; ushort* out[3]; };
__global__ __launch_bounds__(256) void conv_bf16_batch3_kernel(CP3 p, int n8)
{
    const int z = blockIdx.y;
    const int i = blockIdx.x * 256 + threadIdx.x;
    if (i >= n8) return;
    const float4* s4 = (const float4*)(p.in[z] + (size_t)i * 8);
    float4 x = s4[0], y = s4[1];
    us8 v;
    v[0] = f2bf(x.x); v[1] = f2bf(x.y); v[2] = f2bf(x.z); v[3] = f2bf(x.w);
    v[4] = f2bf(y.x); v[5] = f2bf(y.y); v[6] = f2bf(y.z); v[7] = f2bf(y.w);
    ((us8*)p.out[z])[i] = v;
}

struct TP6 { const float* in[6]; ushort* out[6]; int N[6]; };
__global__ __launch_bounds__(256) void transpose_conv_kernel(TP6 p)
{
    const int z = blockIdx.z;
    const int Nn = p.N[z];
    const int n0 = blockIdx.x * 64;
    if (n0 >= Nn) return;
    const int k0 = blockIdx.y * 64;
    const float* in = p.in[z];
    ushort* out = p.out[z];

    __shared__ float tile[64][65];
    const int t = threadIdx.x;
    const int tx = t & 63, ty = t >> 6;
#pragma unroll
    for (int r = 0; r < 16; ++r) {
        const int row = ty * 16 + r;
        tile[row][tx] = in[(size_t)(k0 + row) * Nn + n0 + tx];
    }
    __syncthreads();
    const int n = t >> 2, kq = t & 3;
    us8 v0, v1;
#pragma unroll
    for (int j = 0; j < 8; ++j) v0[j] = f2bf(tile[kq * 16 + j][n]);
#pragma unroll
    for (int j = 0; j < 8; ++j) v1[j] = f2bf(tile[kq * 16 + 8 + j][n]);
    ushort* op = out + (size_t)(n0 + n) * 1024 + k0 + kq * 16;
    *(us8*)op = v0;
    *((us8*)op + 1) = v1;
}

// ---------------------------------------------------------------------------
// R8-proven 128x128 BK=64 4-wave GEMM (single-buffer, XOR swizzle, 0 bank
// conflicts). For hq/gate/LSTM. bf16 split-K partial store.
// ---------------------------------------------------------------------------
template <int NP, int SK>
__global__ __launch_bounds__(256) void gemm_gl(
    const ushort* __restrict__ A0, const ushort* __restrict__ A1, const ushort* __restrict__ A2,
    const ushort* __restrict__ W0, const ushort* __restrict__ W1, const ushort* __restrict__ W2,
    ushort* __restrict__ Cp, int M, int N)
{
    __shared__ ushort As[128 * 64];
    __shared__ ushort Bs[128 * 64];

    const int t = threadIdx.x, l = t & 63, w = t >> 6;
    const int wm = w >> 1, wn = w & 1;
    const int m0 = blockIdx.y * 128, n0 = blockIdx.x * 128;

    const int srow = l >> 3;
    const int csw  = ((l & 7) ^ (l >> 3)) * 8;
    const int kx0 = ((0 + (l >> 4)) ^ (l & 7)) * 8;
    const int kx1 = ((4 + (l >> 4)) ^ (l & 7)) * 8;

    f32x4 acc[4][4];
#pragma unroll
    for (int i = 0; i < 4; ++i)
#pragma unroll
        for (int j = 0; j < 4; ++j) acc[i][j] = (f32x4){0.f, 0.f, 0.f, 0.f};

    const int total = NP * 16;
    const int per   = total / SK;
    const int s0v   = blockIdx.z * per;
    const int sEnd  = s0v + per;

    for (int s = s0v; s < sEnd; ++s) {
        const int p  = (NP == 1) ? 0 : (s >> 4);
        const int k0 = (s & 15) << 6;
        const ushort* Ap = (p == 0) ? A0 : ((p == 1) ? A1 : A2);
        const ushort* Wp = (p == 0) ? W0 : ((p == 1) ? W1 : W2);
#pragma unroll
        for (int j = 0; j < 4; ++j) {
            const int rb = w * 32 + j * 8;
            gll16(Ap + (size_t)(m0 + rb + srow) * 1024 + k0 + csw, &As[rb * 64]);
            gll16(Wp + (size_t)(n0 + rb + srow) * 1024 + k0 + csw, &Bs[rb * 64]);
        }
        __syncthreads();

        short8 aF[4][2], bF[4][2];
#pragma unroll
        for (int mi = 0; mi < 4; ++mi) {
            const int ro = (wm * 64 + mi * 16 + (l & 15)) * 64;
            aF[mi][0] = *(const short8*)&As[ro + kx0];
            aF[mi][1] = *(const short8*)&As[ro + kx1];
        }
#pragma unroll
        for (int ni = 0; ni < 4; ++ni) {
            const int ro = (wn * 64 + ni * 16 + (l & 15)) * 64;
            bF[ni][0] = *(const short8*)&Bs[ro + kx0];
            bF[ni][1] = *(const short8*)&Bs[ro + kx1];
        }
#pragma unroll
        for (int mi = 0; mi < 4; ++mi)
#pragma unroll
            for (int ni = 0; ni < 4; ++ni) {
                acc[mi][ni] = __builtin_amdgcn_mfma_f32_16x16x32_bf16(
                    aF[mi][0], bF[ni][0], acc[mi][ni], 0, 0, 0);
                acc[mi][ni] = __builtin_amdgcn_mfma_f32_16x16x32_bf16(
                    aF[mi][1], bF[ni][1], acc[mi][ni], 0, 0, 0);
            }
        __syncthreads();
    }

    ushort* Cz = Cp + (size_t)blockIdx.z * M * N;
#pragma unroll
    for (int ni = 0; ni < 4; ++ni) {
        const int col = n0 + wn * 64 + ni * 16 + (l & 15);
#pragma unroll
        for (int mi = 0; mi < 4; ++mi) {
            const int row = m0 + wm * 64 + mi * 16 + ((l >> 4) << 2);
#pragma unroll
            for (int r = 0; r < 4; ++r)
                Cz[(size_t)(row + r) * N + col] = f2bf(acc[mi][ni][r]);
        }
    }
}

// ---------------------------------------------------------------------------
// R10-proven attn GEMM: 128x128 BK=32 dbuf, counted vmcnt(4) prefetch,
// pair-swizzle LDS (0 bank conflicts). Fused tanh*Wa2w epilogue.
// ---------------------------------------------------------------------------
__global__ __launch_bounds__(256) void attn_db(
    const ushort* __restrict__ A0, const ushort* __restrict__ W0,
    const float* __restrict__ hq, const float* __restrict__ bv2a,
    const float* __restrict__ Wa2w, float* __restrict__ epart)
{
    __shared__ ushort As[2][128 * 32];   // 2 x 8 KB
    __shared__ ushort Bs[2][128 * 32];   // 2 x 8 KB

    const int t = threadIdx.x, l = t & 63, w = t >> 6;
    const int wm = w >> 1, wn = w & 1;

    // XCD-chunked bijective swizzle: nwg = 4*320 = 1280 = 8*160
    const int lin = blockIdx.y * gridDim.x + blockIdx.x;
    const int swz = (lin & 7) * 160 + (lin >> 3);
    const int bx = swz & 3, by = swz >> 2;
    const int m0 = by * 128, n0 = bx * 128;

    const int srow  = l >> 2;
    const int schnk = ((l & 3) ^ ((l >> 3) & 3)) * 8;

    int aoff[4], boff[4];
#pragma unroll
    for (int mi = 0; mi < 4; ++mi)
        aoff[mi] = (wm * 64 + mi * 16 + (l & 15)) * 32 + (((l >> 4) ^ ((l >> 1) & 3)) * 8);
#pragma unroll
    for (int ni = 0; ni < 4; ++ni)
        boff[ni] = (wn * 64 + ni * 16 + (l & 15)) * 32 + (((l >> 4) ^ ((l >> 1) & 3)) * 8);

    f32x4 acc[4][4];
#pragma unroll
    for (int i = 0; i < 4; ++i)
#pragma unroll
        for (int j = 0; j < 4; ++j) acc[i][j] = (f32x4){0.f, 0.f, 0.f, 0.f};

    auto stage = [&](int s, int buf) {   // 4 gll16 per thread
        const int k0 = s << 5;
#pragma unroll
        for (int j = 0; j < 2; ++j) {
            const int rb = j * 64 + w * 16;
            gll16(A0 + (size_t)(m0 + rb + srow) * 1024 + k0 + schnk, &As[buf][rb * 32]);
            gll16(W0 + (size_t)(n0 + rb + srow) * 1024 + k0 + schnk, &Bs[buf][rb * 32]);
        }
    };

    constexpr int NS = 32;               // K-steps of 32 (K = 1024)
    stage(0, 0);
    int cur = 0;
    for (int s = 0; s < NS; ++s) {
        const bool pf = (s + 1 < NS);
        if (pf) {
            stage(s + 1, cur ^ 1);        // up to 8 outstanding
            asm volatile("s_waitcnt vmcnt(4)" ::: "memory");   // retire tile s
        } else {
            asm volatile("s_waitcnt vmcnt(0)" ::: "memory");
        }
        __builtin_amdgcn_s_barrier();     // buffer cur resident for all waves
        asm volatile("" ::: "memory");

        short8 aF[4], bF[4];
#pragma unroll
        for (int mi = 0; mi < 4; ++mi) aF[mi] = *(const short8*)&As[cur][aoff[mi]];
#pragma unroll
        for (int ni = 0; ni < 4; ++ni) bF[ni] = *(const short8*)&Bs[cur][boff[ni]];
#pragma unroll
        for (int mi = 0; mi < 4; ++mi)
#pragma unroll
            for (int ni = 0; ni < 4; ++ni)
                acc[mi][ni] = __builtin_amdgcn_mfma_f32_16x16x32_bf16(
                    aF[mi], bF[ni], acc[mi][ni], 0, 0, 0);

        asm volatile("" ::: "memory");
        __builtin_amdgcn_s_barrier();     // all waves done reading cur
        asm volatile("" ::: "memory");
        cur ^= 1;
    }

    // ---- fused epilogue: tanh(acc + hq + bv2a) * Wa2w reduced over 128 cols
    float* red = (float*)&As[0][0];       // [128][2]
    float wa[4], bv[4];
    int coln[4];
#pragma unroll
    for (int ni = 0; ni < 4; ++ni) {
        coln[ni] = n0 + wn * 64 + ni * 16 + (l & 15);
        wa[ni] = Wa2w[coln[ni]];
        bv[ni] = bv2a[coln[ni]];
    }
#pragma unroll
    for (int mi = 0; mi < 4; ++mi) {
        const int rowl = wm * 64 + mi * 16 + ((l >> 4) << 2);
#pragma unroll
        for (int r = 0; r < 4; ++r) {
            const int row = m0 + rowl + r;
            const int b = row / LL;
            float v = 0.f;
#pragma unroll
            for (int ni = 0; ni < 4; ++ni) {
                float x = acc[mi][ni][r] + hq[(size_t)b * 512 + coln[ni]] + bv[ni];
                v += ftanh(x) * wa[ni];
            }
            v += __shfl_xor(v, 1);
            v += __shfl_xor(v, 2);
            v += __shfl_xor(v, 4);
            v += __shfl_xor(v, 8);
            if ((l & 15) == 0) red[(rowl + r) * 2 + wn] = v;
        }
    }
    __syncthreads();
    if (t < 128)
        epart[(size_t)(m0 + t) * 4 + bx] = red[t * 2] + red[t * 2 + 1];
}

// ---------------------------------------------------------------------------
__global__ __launch_bounds__(256) void reduce_hq_b_kernel(
    const ushort* __restrict__ part, const float* __restrict__ bias, float* __restrict__ hq)
{
    const int i = blockIdx.x * 256 + threadIdx.x;   // < 1024*512
    float s = bias[i & 511];
#pragma unroll
    for (int z = 0; z < 8; ++z) s += bf2f(part[(size_t)z * 524288 + i]);
    hq[i] = s;
}

__global__ __launch_bounds__(256) void reduce_gate_b_kernel(
    const ushort* __restrict__ part, const float* __restrict__ bias,
    const float* __restrict__ pos, ushort* __restrict__ gpb)
{
    const int i = blockIdx.x * 256 + threadIdx.x;   // < 1024*1024
    float s = bias[i & 1023];
#pragma unroll
    for (int z = 0; z < 4; ++z) s += bf2f(part[(size_t)z * 1048576 + i]);
    const float g = fmaxf(s, 0.f);
    gpb[i] = f2bf(g * pos[i] + pos[i]);
}

// ---------------------------------------------------------------------------
__global__ __launch_bounds__(256) void softmax_af_kernel(
    const float* __restrict__ epart, const ushort* __restrict__ Vb,
    const float* __restrict__ ba2w, ushort* __restrict__ afb)
{
    const int b = blockIdx.x;
    const int tid = threadIdx.x;
    __shared__ float e_raw[LL];
    __shared__ float e_exp[LL];

    if (tid < LL) {
        const float* ep = &epart[(size_t)(b * LL + tid) * 4];
        float e = ba2w[0];
#pragma unroll
        for (int c = 0; c < 4; ++c) e += ep[c];
        e_raw[tid] = e;
    }
    __syncthreads();
    float mx = -1e30f;
#pragma unroll
    for (int ll = 0; ll < LL; ++ll) mx = fmaxf(mx, e_raw[ll]);
    if (tid < LL) e_exp[tid] = __expf(e_raw[tid] - mx);
    __syncthreads();
    float sum = 0.f;
#pragma unroll
    for (int ll = 0; ll < LL; ++ll) sum += e_exp[ll];
    const float inv = 1.f / sum;

    const int r4 = tid * 4;
    const ushort* vp = &Vb[(size_t)b * LL * RR + r4];
    float a0 = 0.f, a1 = 0.f, a2 = 0.f, a3 = 0.f;
#pragma unroll 8
    for (int ll = 0; ll < LL; ++ll) {
        ushort4 v = *(const ushort4*)&vp[(size_t)ll * RR];
        const float wgt = e_exp[ll];
        a0 += wgt * bf2f(v.x); a1 += wgt * bf2f(v.y);
        a2 += wgt * bf2f(v.z); a3 += wgt * bf2f(v.w);
    }
    ushort* op = &afb[(size_t)b * RR + r4];
    op[0] = f2bf(a0 * inv); op[1] = f2bf(a1 * inv);
    op[2] = f2bf(a2 * inv); op[3] = f2bf(a3 * inv);
}

// ---------------------------------------------------------------------------
__global__ __launch_bounds__(256) void lstm_finishb_kernel(
    const ushort* __restrict__ part,
    const float* __restrict__ bi, const float* __restrict__ ba, const float* __restrict__ bh,
    const float* __restrict__ c_in, const float* __restrict__ h_in, const float* __restrict__ mask,
    float* __restrict__ h_out, float* __restrict__ h_out2,
    float* __restrict__ c_out, ushort* __restrict__ h_bf)
{
    const int i = blockIdx.x * 256 + threadIdx.x;  // [0, B*R)
    const int b = i >> 10;
    const int r = i & 1023;
    float sg[4];
#pragma unroll
    for (int g = 0; g < 4; ++g) {
        const int gr = g * 1024 + r;
        float s = bi[gr] + ba[gr] + bh[gr];
#pragma unroll
        for (int z = 0; z < 4; ++z)
            s += bf2f(part[(size_t)z * 4194304 + (size_t)b * 4096 + gr]);
        sg[g] = s;
    }
    const float ig = fsigmoid(sg[0]);
    const float fg = fsigmoid(sg[1]);
    const float og = fsigmoid(sg[2]);
    const float gt = ftanh(sg[3]);
    const float m = mask[b];
    const float c = c_in[i];
    float cn = fg * c + ig * gt;
    cn = cn * m + c * (1.f - m);
    const float h = h_in[i];
    float hn = og * ftanh(cn);
    hn = hn * m + h * (1.f - m);
    h_out[i] = hn;
    if (h_out2) h_out2[i] = hn;
    c_out[i] = cn;
    if (h_bf) h_bf[i] = f2bf(hn);
}

extern "C" void kernel_launch(void* const* d_in, const int* in_sizes, int n_in,
                              void* d_out, int out_size, void* d_ws, size_t ws_size,
                              hipStream_t stream) {
    const float* xt   = (const float*)d_in[0];
    const float* mask = (const float*)d_in[1];
    const float* V    = (const float*)d_in[2];
    const float* pos  = (const float*)d_in[3];
    const float* h1   = (const float*)d_in[4];
    const float* c1   = (const float*)d_in[5];
    const float* h2   = (const float*)d_in[6];
    const float* c2   = (const float*)d_in[7];
    const float* Wg   = (const float*)d_in[8];
    const float* bg   = (const float*)d_in[9];
    const float* Wi1  = (const float*)d_in[10];
    const float* bi1  = (const float*)d_in[11];
    const float* Wa1  = (const float*)d_in[12];
    const float* ba1  = (const float*)d_in[13];
    const float* Wh1  = (const float*)d_in[14];
    const float* bh1  = (const float*)d_in[15];
    const float* Wi2  = (const float*)d_in[16];
    const float* bi2  = (const float*)d_in[17];
    const float* Wa2  = (const float*)d_in[18];
    const float* ba2  = (const float*)d_in[19];
    const float* Wh2  = (const float*)d_in[20];
    const float* bh2  = (const float*)d_in[21];
    const float* Wv2a = (const float*)d_in[22];
    const float* bv2a = (const float*)d_in[23];
    const float* Wh2a = (const float*)d_in[24];
    const float* bh2a = (const float*)d_in[25];
    const float* Wa2w = (const float*)d_in[26];
    const float* ba2w = (const float*)d_in[27];

    float* out = (float*)d_out;
    float* out2  = out;
    float* out1  = out + (size_t)BB * RR;
    float* c1n   = out + 2 * (size_t)BB * RR;
    float* out2b = out + 3 * (size_t)BB * RR;
    float* c2n   = out + 4 * (size_t)BB * RR;

    // ---- workspace ----
    ushort* wsu = (ushort*)d_ws;
    size_t o = 0;
    ushort* Vb     = wsu + o; o += (size_t)40960 * 1024;   // 84 MB
    ushort* Wh2aT0 = wsu + o; o += (size_t)512 * 1024;
    ushort* Wh2aT1 = wsu + o; o += (size_t)512 * 1024;
    ushort* WgT    = wsu + o; o += (size_t)1024 * 1024;
    ushort* Wv2aT  = wsu + o; o += (size_t)512 * 1024;
    ushort* Wi1T   = wsu + o; o += (size_t)4096 * 1024;
    ushort* Wa1T   = wsu + o; o += (size_t)4096 * 1024;
    ushort* Wh1T   = wsu + o; o += (size_t)4096 * 1024;
    ushort* Wi2T   = wsu + o; o += (size_t)4096 * 1024;
    ushort* Wa2T   = wsu + o; o += (size_t)4096 * 1024;
    ushort* Wh2T   = wsu + o; o += (size_t)4096 * 1024;
    ushort* xtb    = wsu + o; o += (size_t)1024 * 1024;
    ushort* h1b    = wsu + o; o += (size_t)1024 * 1024;
    ushort* h2b    = wsu + o; o += (size_t)1024 * 1024;
    ushort* gpb    = wsu + o; o += (size_t)1024 * 1024;
    ushort* afb    = wsu + o; o += (size_t)1024 * 1024;
    ushort* out1b  = wsu + o; o += (size_t)1024 * 1024;
    ushort* partSb = wsu + o; o += (size_t)8 * 1024 * 512; // hq x8 / gate x4 bf16 partials
    float* wsf    = (float*)(wsu + o);
    float* hqf    = wsf;                   // 524288
    float* epart  = hqf + 524288;          // 40960*4
    // LSTM bf16 partials (4 x 1024 x 4096 ushort = 32 MB) alias Vb (dead after softmax_af)
    ushort* partKb = Vb;

    const dim3 blk(256);

    // ---- conversion / transpose passes ----
    conv_bf16_kernel<<<dim3(20480), blk, 0, stream>>>(V, Vb, 5242880);
    {
        CP3 p; p.in[0] = xt; p.in[1] = h1; p.in[2] = h2;
        p.out[0] = xtb; p.out[1] = h1b; p.out[2] = h2b;
        conv_bf16_batch3_kernel<<<dim3(512, 3), blk, 0, stream>>>(p, 131072);
    }
    {
        TP6 p;
        p.in[0] = Wi1; p.in[1] = Wa1; p.in[2] = Wh1;
        p.in[3] = Wi2; p.in[4] = Wa2; p.in[5] = Wh2;
        p.out[0] = Wi1T; p.out[1] = Wa1T; p.out[2] = Wh1T;
        p.out[3] = Wi2T; p.out[4] = Wa2T; p.out[5] = Wh2T;
        for (int z = 0; z < 6; ++z) p.N[z] = 4096;
        transpose_conv_kernel<<<dim3(64, 16, 6), blk, 0, stream>>>(p);
    }
    {
        TP6 p;
        p.in[0] = Wh2a; p.in[1] = Wh2a + (size_t)1024 * 512;
        p.in[2] = Wg;   p.in[3] = Wv2a;
        p.out[0] = Wh2aT0; p.out[1] = Wh2aT1; p.out[2] = WgT; p.out[3] = Wv2aT;
        p.N[0] = 512; p.N[1] = 512; p.N[2] = 1024; p.N[3] = 512;
        p.in[4] = nullptr; p.in[5] = nullptr; p.out[4] = nullptr; p.out[5] = nullptr;
        p.N[4] = 0; p.N[5] = 0;
        transpose_conv_kernel<<<dim3(16, 16, 4), blk, 0, stream>>>(p);
    }

    // ---- hq = [h1,h2] @ Wh2a (split-K x8, bf16 partials) + bias reduce ----
    gemm_gl<2, 8><<<dim3(4, 8, 8), blk, 0, stream>>>(
        h1b, h2b, nullptr, Wh2aT0, Wh2aT1, nullptr, partSb, 1024, 512);
    reduce_hq_b_kernel<<<dim3(2048), blk, 0, stream>>>(partSb, bh2a, hqf);

    // ---- gate: xt @ Wg (split-K x4, bf16 partials), relu*pos+pos -> bf16 ----
    gemm_gl<1, 4><<<dim3(8, 8, 4), blk, 0, stream>>>(
        xtb, nullptr, nullptr, WgT, nullptr, nullptr, partSb, 1024, 1024);
    reduce_gate_b_kernel<<<dim3(4096), blk, 0, stream>>>(partSb, bg, pos, gpb);

    // ---- attention scores: dbuf Vb @ Wv2a, fused tanh-reduce -> epart ----
    attn_db<<<dim3(4, 320), blk, 0, stream>>>(
        Vb, Wv2aT, hqf, bv2a, Wa2w, epart);
    softmax_af_kernel<<<dim3(BB), blk, 0, stream>>>(epart, Vb, ba2w, afb);

    // ---- LSTM layer 1 (split-K x4 over fused K = xt|gp|h1, bf16 partials) ----
    gemm_gl<3, 4><<<dim3(32, 8, 4), blk, 0, stream>>>(
        xtb, gpb, h1b, Wi1T, Wa1T, Wh1T, partKb, 1024, 4096);
    lstm_finishb_kernel<<<dim3(4096), blk, 0, stream>>>(
        partKb, bi1, ba1, bh1, c1, h1, mask, out1, nullptr, c1n, out1b);

    // ---- LSTM layer 2 (split-K x4 over fused K = out1|af|h2) ----
    gemm_gl<3, 4><<<dim3(32, 8, 4), blk, 0, stream>>>(
        out1b, afb, h2b, Wi2T, Wa2T, Wh2T, partKb, 1024, 4096);
    lstm_finishb_kernel<<<dim3(4096), blk, 0, stream>>>(
        partKb, bi2, ba2, bh2, c2, h2, mask, out2, out2b, c2n, nullptr);
}